// Round 18
// baseline (193.416 us; speedup 1.0000x reference)
//
#include <hip/hip_runtime.h>
#include <hip/hip_bf16.h>

typedef float f4 __attribute__((ext_vector_type(4)));
typedef unsigned short us;
typedef unsigned int uint32;
typedef _Float16 h16;

union h2u { uint32 u; h16 h[2]; };
union u2h { uint2 v; h16 h[4]; };
__device__ inline uint32 pack2h(float a, float b) { h2u x; x.h[0] = (h16)a; x.h[1] = (h16)b; return x.u; }

#define BSH 8            // 256 nodes per bucket
#define CHUNK 4096       // edges per sort workgroup
#define CAP 6144         // max edges per bucket (mean 4096, +32 sigma)

// ---------------- pass A: global bucket counts ----------------
__global__ __launch_bounds__(256) void bcount_k(const int* __restrict__ dst, int* __restrict__ bcnt,
                                                int E, int B) {
    __shared__ int hist[512];
    int tid = threadIdx.x;
    for (int i = tid; i < 512; i += 256) hist[i] = 0;
    __syncthreads();
    int base = blockIdx.x * CHUNK;
    int n = min(CHUNK, E - base);
    for (int i = tid; i < n; i += 256) atomicAdd(&hist[dst[base + i] >> BSH], 1);
    __syncthreads();
    for (int i = tid; i < B; i += 256) if (hist[i]) atomicAdd(&bcnt[i], hist[i]);
}

// ---------------- pass B: exclusive scan of bucket counts (B <= 512) ----------------
__global__ __launch_bounds__(256) void bscan_k(const int* __restrict__ bcnt, int* __restrict__ gbase,
                                               int* __restrict__ gcur, int B, int E) {
    __shared__ int sa[512], sb[512];
    int tid = threadIdx.x;
    #pragma unroll
    for (int k = 0; k < 2; ++k) { int i = tid + k * 256; sa[i] = (i < B) ? bcnt[i] : 0; }
    __syncthreads();
    int* c = sa; int* nx = sb;
    for (int off = 1; off < 512; off <<= 1) {
        #pragma unroll
        for (int k = 0; k < 2; ++k) { int i = tid + k * 256; nx[i] = c[i] + (i >= off ? c[i - off] : 0); }
        __syncthreads();
        int* t = c; c = nx; nx = t;
    }
    #pragma unroll
    for (int k = 0; k < 2; ++k) {
        int i = tid + k * 256;
        if (i < B) { int ex = c[i] - bcnt[i]; gbase[i] = ex; gcur[i] = ex; }
    }
    if (tid == 0) gbase[B] = E;
}

// ---------------- pass C: chunked counting sort -> bucket-grouped packed edges ----------------
// bedge[pos] = (src << 8) | (dst & 255), grouped by bucket (dst >> 8). Requires src < 2^24.
__global__ __launch_bounds__(256) void bscat_k(const int* __restrict__ src, const int* __restrict__ dst,
                                               int* __restrict__ gcur, unsigned int* __restrict__ bedge,
                                               int E, int B) {
    __shared__ int hist[512], lbase[512], cur2[512], gb[512];
    __shared__ int sa[512], sb[512];
    __shared__ unsigned int sedge[CHUNK];
    __shared__ unsigned short posb[CHUNK];
    int tid = threadIdx.x;
    int base = blockIdx.x * CHUNK;
    int n = min(CHUNK, E - base);
    for (int i = tid; i < 512; i += 256) hist[i] = 0;
    __syncthreads();
    for (int i = tid; i < n; i += 256) atomicAdd(&hist[dst[base + i] >> BSH], 1);
    __syncthreads();
    #pragma unroll
    for (int k = 0; k < 2; ++k) { int i = tid + k * 256; sa[i] = hist[i]; }
    __syncthreads();
    int* c = sa; int* nx = sb;
    for (int off = 1; off < 512; off <<= 1) {
        #pragma unroll
        for (int k = 0; k < 2; ++k) { int i = tid + k * 256; nx[i] = c[i] + (i >= off ? c[i - off] : 0); }
        __syncthreads();
        int* t = c; c = nx; nx = t;
    }
    #pragma unroll
    for (int k = 0; k < 2; ++k) {
        int i = tid + k * 256;
        int ex = c[i] - hist[i];
        lbase[i] = ex; cur2[i] = ex;
        if (i < B) gb[i] = hist[i] ? atomicAdd(&gcur[i], hist[i]) : 0;
    }
    for (int t = tid; t < B; t += 256) {
        int e0 = lbase[t], e1 = e0 + hist[t];
        for (int j = e0; j < e1; ++j) posb[j] = (unsigned short)t;
    }
    __syncthreads();
    for (int i = tid; i < n; i += 256) {
        int d = dst[base + i];
        int s = src[base + i];
        int b = d >> BSH;
        int p = atomicAdd(&cur2[b], 1);
        sedge[p] = ((unsigned int)s << BSH) | (unsigned int)(d & ((1 << BSH) - 1));
    }
    __syncthreads();
    for (int i = tid; i < n; i += 256) {
        int b = posb[i];
        bedge[gb[b] + (i - lbase[b])] = sedge[i];
    }
}

// ---------------- pass D: per-bucket CSR + degrees + dinv, all coalesced ----------------
__global__ __launch_bounds__(256) void bcsr_k(const unsigned int* __restrict__ bedge,
                                              const int* __restrict__ gbase,
                                              int* __restrict__ row_ptr, int* __restrict__ cnt,
                                              float* __restrict__ dinv, int* __restrict__ col,
                                              int N, int B) {
    __shared__ int hist[256], lofs[256], cur2[256];
    __shared__ int sa[256], sb[256];
    __shared__ int cols[CAP];
    int b = blockIdx.x, tid = threadIdx.x;
    int node0 = b << BSH;
    int g0 = gbase[b], g1 = gbase[b + 1];
    int n = g1 - g0;
    hist[tid] = 0;
    __syncthreads();
    for (int i = tid; i < n; i += 256) atomicAdd(&hist[bedge[g0 + i] & 255], 1);
    __syncthreads();
    sa[tid] = hist[tid];
    __syncthreads();
    int* c = sa; int* nx = sb;
    for (int off = 1; off < 256; off <<= 1) {
        nx[tid] = c[tid] + (tid >= off ? c[tid - off] : 0);
        __syncthreads();
        int* t = c; c = nx; nx = t;
    }
    int ex = c[tid] - hist[tid];
    lofs[tid] = ex; cur2[tid] = ex;
    int node = node0 + tid;
    if (node < N) {
        int deg = hist[tid];
        cnt[node] = deg;
        row_ptr[node] = g0 + ex;
        dinv[node] = rsqrtf((float)(deg + 1));
    }
    __syncthreads();
    for (int i = tid; i < n; i += 256) {
        unsigned int e = bedge[g0 + i];
        int p = atomicAdd(&cur2[e & 255], 1);
        if (p < CAP) cols[p] = (int)(e >> BSH);
    }
    __syncthreads();
    for (int i = tid; i < n; i += 256) col[g0 + i] = (i < CAP) ? cols[i] : 0;
}

// ---------------- graph boundaries from sorted batch ----------------
__global__ __launch_bounds__(256) void gbound_k(const int* __restrict__ batch, int* __restrict__ gstart,
                                                int N, int G) {
    int i = blockIdx.x * 256 + threadIdx.x;
    if (i >= N) return;
    int b = batch[i];
    int prev = (i == 0) ? -1 : batch[i - 1];
    for (int g = prev + 1; g <= b; ++g) gstart[g] = i;
    if (i == N - 1) {
        for (int g = b + 1; g <= G; ++g) gstart[g] = N;
    }
}

// ---------------- GEMM1: hs_h = fp16( dinv[r] * (x @ W1) ),  [N,128]@[128,64] ----------------
__global__ __launch_bounds__(256) void gemm1_k(const float* __restrict__ x, const float* __restrict__ W1,
                                               const float* __restrict__ dinv, h16* __restrict__ hsh, int N) {
    __shared__ float xT[128][64];   // k-major x tile
    __shared__ float wS[128][64];
    const int tid = threadIdx.x;
    const int row0 = blockIdx.x * 64;

    {   // W1: 8192 floats = 2048 f4, contiguous
        const f4* wsrc = (const f4*)W1;
        f4* wdst = (f4*)&wS[0][0];
        #pragma unroll
        for (int i = 0; i < 8; ++i) wdst[tid + i * 256] = wsrc[tid + i * 256];
    }
    {   // x tile rows row0..row0+63, transposed into LDS
        #pragma unroll
        for (int it = 0; it < 8; ++it) {
            int i = tid + it * 256;      // 0..2047
            int r = i & 63;
            int k4 = (i >> 6) * 4;       // 0..124
            int row = row0 + r;
            f4 v = (f4)(0.0f);
            if (row < N) v = *(const f4*)(x + (size_t)row * 128 + k4);
            xT[k4 + 0][r] = v.x; xT[k4 + 1][r] = v.y;
            xT[k4 + 2][r] = v.z; xT[k4 + 3][r] = v.w;
        }
    }
    __syncthreads();

    const int rl = (tid & 15) * 4;    // local rows rl..rl+3
    const int c0 = (tid >> 4) * 4;    // cols c0..c0+3
    f4 acc0 = (f4)(0.0f), acc1 = (f4)(0.0f), acc2 = (f4)(0.0f), acc3 = (f4)(0.0f);
    #pragma unroll 8
    for (int k = 0; k < 128; ++k) {
        f4 xa = *(const f4*)&xT[k][rl];
        f4 wb = *(const f4*)&wS[k][c0];
        acc0 += xa.x * wb;
        acc1 += xa.y * wb;
        acc2 += xa.z * wb;
        acc3 += xa.w * wb;
    }
    #pragma unroll
    for (int i = 0; i < 4; ++i) {
        int row = row0 + rl + i;
        if (row < N) {
            float di = dinv[row];
            f4 a = (i == 0) ? acc0 : (i == 1) ? acc1 : (i == 2) ? acc2 : acc3;
            a *= di;
            uint2 p;
            p.x = pack2h(a.x, a.y);
            p.y = pack2h(a.z, a.w);
            *(uint2*)(hsh + (size_t)row * 64 + c0) = p;
        }
    }
}

// ---------------- AGG1+GEMM2 fused: wave per node, uint2 (4 fp16 ch) per lane ----------------
// Gather: q = lane&15 -> channels 4q..4q+3; g = lane>>4 -> edge subgroup 0..3.
// 32-edge unroll: 8 independent 512B loads issued back-to-back (32 rows in flight/wave).
__global__ __launch_bounds__(256) void agg1_k(const h16* __restrict__ hsh, const int* __restrict__ row_ptr,
                                              const int* __restrict__ cnt, const int* __restrict__ col,
                                              const float* __restrict__ dinv, const float* __restrict__ b1,
                                              const float* __restrict__ W2, float* __restrict__ h2s, int N) {
    int wid = blockIdx.x * 4 + (threadIdx.x >> 6);
    int lane = threadIdx.x & 63;
    if (wid >= N) return;
    const int c16 = lane & 15;      // output channel (for the fused dot)
    const int hh  = lane >> 4;      // k-quarter 0..3
    float wreg[16];
    #pragma unroll
    for (int k = 0; k < 16; ++k) wreg[k] = W2[(hh * 16 + k) * 16 + c16];
    float bias = b1[lane];

    const int q = lane & 15;        // channel quad: channels 4q..4q+3
    const int g = lane >> 4;        // edge subgroup 0..3
    const uint2* rowb = (const uint2*)hsh + q;   // + s*16 = row s, channels 4q..4q+3

    int beg = row_ptr[wid];
    int num = cnt[wid];
    float a0 = 0.0f, a1 = 0.0f, a2 = 0.0f, a3 = 0.0f;
    for (int e0 = 0; e0 < num; e0 += 64) {
        int rem = num - e0;
        int el = 0;
        if (lane < rem) el = col[beg + e0 + lane];
        int m = rem < 64 ? rem : 64;
        int e = 0;
        for (; e + 32 <= m; e += 32) {   // subgroup g: 8 edges, all loads issued before converts
            int s0 = __shfl(el, e + g);
            int s1 = __shfl(el, e + 4 + g);
            int s2 = __shfl(el, e + 8 + g);
            int s3 = __shfl(el, e + 12 + g);
            int s4 = __shfl(el, e + 16 + g);
            int s5 = __shfl(el, e + 20 + g);
            int s6 = __shfl(el, e + 24 + g);
            int s7 = __shfl(el, e + 28 + g);
            u2h u0, u1, u2, u3, u4, u5, u6, u7;
            u0.v = rowb[(size_t)s0 * 16];
            u1.v = rowb[(size_t)s1 * 16];
            u2.v = rowb[(size_t)s2 * 16];
            u3.v = rowb[(size_t)s3 * 16];
            u4.v = rowb[(size_t)s4 * 16];
            u5.v = rowb[(size_t)s5 * 16];
            u6.v = rowb[(size_t)s6 * 16];
            u7.v = rowb[(size_t)s7 * 16];
            a0 += ((float)u0.h[0] + (float)u1.h[0]) + ((float)u2.h[0] + (float)u3.h[0]);
            a1 += ((float)u0.h[1] + (float)u1.h[1]) + ((float)u2.h[1] + (float)u3.h[1]);
            a2 += ((float)u0.h[2] + (float)u1.h[2]) + ((float)u2.h[2] + (float)u3.h[2]);
            a3 += ((float)u0.h[3] + (float)u1.h[3]) + ((float)u2.h[3] + (float)u3.h[3]);
            a0 += ((float)u4.h[0] + (float)u5.h[0]) + ((float)u6.h[0] + (float)u7.h[0]);
            a1 += ((float)u4.h[1] + (float)u5.h[1]) + ((float)u6.h[1] + (float)u7.h[1]);
            a2 += ((float)u4.h[2] + (float)u5.h[2]) + ((float)u6.h[2] + (float)u7.h[2]);
            a3 += ((float)u4.h[3] + (float)u5.h[3]) + ((float)u6.h[3] + (float)u7.h[3]);
        }
        for (; e + 16 <= m; e += 16) {   // subgroup g: edges e+g, e+4+g, e+8+g, e+12+g
            int s0 = __shfl(el, e + g);
            int s1 = __shfl(el, e + 4 + g);
            int s2 = __shfl(el, e + 8 + g);
            int s3 = __shfl(el, e + 12 + g);
            u2h u0, u1, u2, u3;
            u0.v = rowb[(size_t)s0 * 16];
            u1.v = rowb[(size_t)s1 * 16];
            u2.v = rowb[(size_t)s2 * 16];
            u3.v = rowb[(size_t)s3 * 16];
            a0 += ((float)u0.h[0] + (float)u1.h[0]) + ((float)u2.h[0] + (float)u3.h[0]);
            a1 += ((float)u0.h[1] + (float)u1.h[1]) + ((float)u2.h[1] + (float)u3.h[1]);
            a2 += ((float)u0.h[2] + (float)u1.h[2]) + ((float)u2.h[2] + (float)u3.h[2]);
            a3 += ((float)u0.h[3] + (float)u1.h[3]) + ((float)u2.h[3] + (float)u3.h[3]);
        }
        for (; e + 4 <= m; e += 4) {     // subgroup g: edge e+g
            int s = __shfl(el, e + g);
            u2h u; u.v = rowb[(size_t)s * 16];
            a0 += (float)u.h[0];
            a1 += (float)u.h[1];
            a2 += (float)u.h[2];
            a3 += (float)u.h[3];
        }
        if (e + g < m) {                 // leftover 1..3 edges: subgroup g takes edge e+g
            int s = __shfl(el, e + g);
            u2h u; u.v = rowb[(size_t)s * 16];
            a0 += (float)u.h[0];
            a1 += (float)u.h[1];
            a2 += (float)u.h[2];
            a3 += (float)u.h[3];
        }
    }
    // merge the four edge subgroups (lane bits 4,5)
    a0 += __shfl_xor(a0, 16); a1 += __shfl_xor(a1, 16); a2 += __shfl_xor(a2, 16); a3 += __shfl_xor(a3, 16);
    a0 += __shfl_xor(a0, 32); a1 += __shfl_xor(a1, 32); a2 += __shfl_xor(a2, 32); a3 += __shfl_xor(a3, 32);
    // redistribute channel quads -> lane = channel (channel c held by lane c>>2, slot c&3)
    float r0 = __shfl(a0, lane >> 2);
    float r1 = __shfl(a1, lane >> 2);
    float r2 = __shfl(a2, lane >> 2);
    float r3 = __shfl(a3, lane >> 2);
    int sl = lane & 3;
    float acc = (sl == 0) ? r0 : (sl == 1) ? r1 : (sl == 2) ? r2 : r3;

    float di = dinv[wid];
    float self = (float)hsh[(size_t)wid * 64 + lane];
    float h1v = tanhf(di * (acc + self) + bias);

    // fused h1_row @ W2: lane (hh,c16) does k = hh*16..hh*16+15, then butterfly-add quarters
    float p = 0.0f;
    #pragma unroll
    for (int k = 0; k < 16; ++k) {
        float hv = __shfl(h1v, hh * 16 + k);
        p += hv * wreg[k];
    }
    p += __shfl_xor(p, 16);
    p += __shfl_xor(p, 32);
    if (lane < 16) h2s[(size_t)wid * 16 + lane] = di * p;
}

// ---------------- AGG2: 16 channels, quarter-wave per node, 4-edge unroll for MLP ----------------
__global__ __launch_bounds__(256) void agg2_k(const float* __restrict__ h2s, const int* __restrict__ row_ptr,
                                              const int* __restrict__ cnt, const int* __restrict__ col,
                                              const float* __restrict__ dinv, const float* __restrict__ b2,
                                              float* __restrict__ h2, int N) {
    int t = blockIdx.x * 256 + threadIdx.x;
    int node = t >> 4;
    int c = t & 15;
    int sub = (threadIdx.x >> 4) & 3;   // quarter within wave
    if (node >= N) return;
    int beg = row_ptr[node];
    int num = cnt[node];
    float acc = 0.0f;
    for (int e0 = 0; e0 < num; e0 += 16) {
        int rem = num - e0;
        int el = 0;
        if (c < rem) el = col[beg + e0 + c];
        int m = rem < 16 ? rem : 16;
        int e = 0;
        for (; e + 8 <= m; e += 8) {       // 8 independent loads in flight
            int s0 = __shfl(el, (sub << 4) + e + 0);
            int s1 = __shfl(el, (sub << 4) + e + 1);
            int s2 = __shfl(el, (sub << 4) + e + 2);
            int s3 = __shfl(el, (sub << 4) + e + 3);
            int s4 = __shfl(el, (sub << 4) + e + 4);
            int s5 = __shfl(el, (sub << 4) + e + 5);
            int s6 = __shfl(el, (sub << 4) + e + 6);
            int s7 = __shfl(el, (sub << 4) + e + 7);
            float v0 = h2s[(size_t)s0 * 16 + c];
            float v1 = h2s[(size_t)s1 * 16 + c];
            float v2 = h2s[(size_t)s2 * 16 + c];
            float v3 = h2s[(size_t)s3 * 16 + c];
            float v4 = h2s[(size_t)s4 * 16 + c];
            float v5 = h2s[(size_t)s5 * 16 + c];
            float v6 = h2s[(size_t)s6 * 16 + c];
            float v7 = h2s[(size_t)s7 * 16 + c];
            acc += (v0 + v1) + (v2 + v3);
            acc += (v4 + v5) + (v6 + v7);
        }
        for (; e + 4 <= m; e += 4) {
            int s0 = __shfl(el, (sub << 4) + e + 0);
            int s1 = __shfl(el, (sub << 4) + e + 1);
            int s2 = __shfl(el, (sub << 4) + e + 2);
            int s3 = __shfl(el, (sub << 4) + e + 3);
            float v0 = h2s[(size_t)s0 * 16 + c];
            float v1 = h2s[(size_t)s1 * 16 + c];
            float v2 = h2s[(size_t)s2 * 16 + c];
            float v3 = h2s[(size_t)s3 * 16 + c];
            acc += (v0 + v1) + (v2 + v3);
        }
        for (; e < m; ++e) {
            int s = __shfl(el, (sub << 4) + e);
            acc += h2s[(size_t)s * 16 + c];
        }
    }
    float di = dinv[node];
    float self = h2s[(size_t)node * 16 + c];
    h2[(size_t)node * 16 + c] = tanhf(di * (acc + self) + b2[c]);
}

// ---------------- segmented pool + sigmoid: one block per graph ----------------
__global__ __launch_bounds__(256) void pool_seg_k(const float* __restrict__ h2, const int* __restrict__ gstart,
                                                  float* __restrict__ out) {
    __shared__ float sd[16][16];   // [node-lane][channel]
    int g = blockIdx.x;
    int beg = gstart[g], end = gstart[g + 1];
    int tid = threadIdx.x;
    int c = tid & 15, r = tid >> 4;
    float acc = 0.0f;
    for (int i = beg + r; i < end; i += 16)
        acc += h2[(size_t)i * 16 + c];
    sd[r][c] = acc;
    __syncthreads();
    if (r < 8) sd[r][c] += sd[r + 8][c];
    __syncthreads();
    if (r < 4) sd[r][c] += sd[r + 4][c];
    __syncthreads();
    if (r < 2) sd[r][c] += sd[r + 2][c];
    __syncthreads();
    if (r == 0) {
        float m = (sd[0][c] + sd[1][c]) / fmaxf((float)(end - beg), 1.0f);
        out[g * 16 + c] = 1.0f / (1.0f + expf(-m));
    }
}

extern "C" void kernel_launch(void* const* d_in, const int* in_sizes, int n_in,
                              void* d_out, int out_size, void* d_ws, size_t ws_size,
                              hipStream_t stream) {
    const float* x     = (const float*)d_in[0];
    const int*   ei    = (const int*)d_in[1];
    const int*   batch = (const int*)d_in[2];
    const float* W1    = (const float*)d_in[3];
    const float* b1    = (const float*)d_in[4];
    const float* W2    = (const float*)d_in[5];
    const float* b2    = (const float*)d_in[6];
    float* out = (float*)d_out;

    const int N = in_sizes[2];
    const int E = in_sizes[1] / 2;
    const int G = out_size / 16;
    const int* src = ei;
    const int* dst = ei + E;

    const int B = (N + 255) >> 8;              // 391 buckets (must be <= 512)
    const int nchunk = (E + CHUNK - 1) / CHUNK;

    char* w = (char*)d_ws;
    int*   bcnt     = (int*)w;    w += 512 * 4;
    int*   gbase    = (int*)w;    w += 520 * 4;
    int*   gcur     = (int*)w;    w += 512 * 4;
    int*   row_ptr  = (int*)w;    w += (size_t)N * 4;
    int*   cnt      = (int*)w;    w += (size_t)N * 4;
    float* dinv     = (float*)w;  w += (size_t)N * 4;
    int*   gstart   = (int*)w;    w += 528 * 4;          // padded so hsh stays 8B-aligned
    int*   col      = (int*)w;    w += (size_t)E * 4;
    h16*   hsh      = (h16*)w;    w += (size_t)N * 64 * 2;
    float* h2s      = (float*)w;  w += (size_t)N * 16 * 4;
    float* h2       = (float*)w;  w += (size_t)N * 16 * 4;
    unsigned int* bedge = (unsigned int*)w;  w += (size_t)E * 4;

    hipMemsetAsync(bcnt, 0, 512 * 4, stream);

    bcount_k<<<nchunk, 256, 0, stream>>>(dst, bcnt, E, B);
    bscan_k <<<1, 256, 0, stream>>>(bcnt, gbase, gcur, B, E);
    bscat_k <<<nchunk, 256, 0, stream>>>(src, dst, gcur, bedge, E, B);
    bcsr_k  <<<B, 256, 0, stream>>>(bedge, gbase, row_ptr, cnt, dinv, col, N, B);
    gbound_k<<<(N + 255) / 256, 256, 0, stream>>>(batch, gstart, N, G);

    gemm1_k <<<(N + 63) / 64, 256, 0, stream>>>(x, W1, dinv, hsh, N);
    agg1_k  <<<(N + 3) / 4, 256, 0, stream>>>(hsh, row_ptr, cnt, col, dinv, b1, W2, h2s, N);
    agg2_k  <<<((size_t)N * 16 + 255) / 256, 256, 0, stream>>>(h2s, row_ptr, cnt, col, dinv, b2, h2, N);
    pool_seg_k<<<G, 256, 0, stream>>>(h2, gstart, out);
}

// Round 19
// 180.020 us; speedup vs baseline: 1.0744x; 1.0744x over previous
//
#include <hip/hip_runtime.h>
#include <hip/hip_bf16.h>

typedef float f4 __attribute__((ext_vector_type(4)));
typedef unsigned short us;
typedef unsigned int uint32;
typedef _Float16 h16;

union h2u { uint32 u; h16 h[2]; };
__device__ inline uint32 pack2h(float a, float b) { h2u x; x.h[0] = (h16)a; x.h[1] = (h16)b; return x.u; }

#define BSH 8            // 256 nodes per bucket
#define CHUNK 4096       // edges per sort workgroup
#define CAP 6144         // max edges per bucket (mean 4096, +32 sigma)

// ---------------- pass A: global bucket counts ----------------
__global__ __launch_bounds__(256) void bcount_k(const int* __restrict__ dst, int* __restrict__ bcnt,
                                                int E, int B) {
    __shared__ int hist[512];
    int tid = threadIdx.x;
    for (int i = tid; i < 512; i += 256) hist[i] = 0;
    __syncthreads();
    int base = blockIdx.x * CHUNK;
    int n = min(CHUNK, E - base);
    for (int i = tid; i < n; i += 256) atomicAdd(&hist[dst[base + i] >> BSH], 1);
    __syncthreads();
    for (int i = tid; i < B; i += 256) if (hist[i]) atomicAdd(&bcnt[i], hist[i]);
}

// ---------------- pass B: exclusive scan of bucket counts (B <= 512) ----------------
__global__ __launch_bounds__(256) void bscan_k(const int* __restrict__ bcnt, int* __restrict__ gbase,
                                               int* __restrict__ gcur, int B, int E) {
    __shared__ int sa[512], sb[512];
    int tid = threadIdx.x;
    #pragma unroll
    for (int k = 0; k < 2; ++k) { int i = tid + k * 256; sa[i] = (i < B) ? bcnt[i] : 0; }
    __syncthreads();
    int* c = sa; int* nx = sb;
    for (int off = 1; off < 512; off <<= 1) {
        #pragma unroll
        for (int k = 0; k < 2; ++k) { int i = tid + k * 256; nx[i] = c[i] + (i >= off ? c[i - off] : 0); }
        __syncthreads();
        int* t = c; c = nx; nx = t;
    }
    #pragma unroll
    for (int k = 0; k < 2; ++k) {
        int i = tid + k * 256;
        if (i < B) { int ex = c[i] - bcnt[i]; gbase[i] = ex; gcur[i] = ex; }
    }
    if (tid == 0) gbase[B] = E;
}

// ---------------- pass C: chunked counting sort -> bucket-grouped packed edges ----------------
// bedge[pos] = (src << 8) | (dst & 255), grouped by bucket (dst >> 8). Requires src < 2^24.
__global__ __launch_bounds__(256) void bscat_k(const int* __restrict__ src, const int* __restrict__ dst,
                                               int* __restrict__ gcur, unsigned int* __restrict__ bedge,
                                               int E, int B) {
    __shared__ int hist[512], lbase[512], cur2[512], gb[512];
    __shared__ int sa[512], sb[512];
    __shared__ unsigned int sedge[CHUNK];
    __shared__ unsigned short posb[CHUNK];
    int tid = threadIdx.x;
    int base = blockIdx.x * CHUNK;
    int n = min(CHUNK, E - base);
    for (int i = tid; i < 512; i += 256) hist[i] = 0;
    __syncthreads();
    for (int i = tid; i < n; i += 256) atomicAdd(&hist[dst[base + i] >> BSH], 1);
    __syncthreads();
    #pragma unroll
    for (int k = 0; k < 2; ++k) { int i = tid + k * 256; sa[i] = hist[i]; }
    __syncthreads();
    int* c = sa; int* nx = sb;
    for (int off = 1; off < 512; off <<= 1) {
        #pragma unroll
        for (int k = 0; k < 2; ++k) { int i = tid + k * 256; nx[i] = c[i] + (i >= off ? c[i - off] : 0); }
        __syncthreads();
        int* t = c; c = nx; nx = t;
    }
    #pragma unroll
    for (int k = 0; k < 2; ++k) {
        int i = tid + k * 256;
        int ex = c[i] - hist[i];
        lbase[i] = ex; cur2[i] = ex;
        if (i < B) gb[i] = hist[i] ? atomicAdd(&gcur[i], hist[i]) : 0;
    }
    for (int t = tid; t < B; t += 256) {
        int e0 = lbase[t], e1 = e0 + hist[t];
        for (int j = e0; j < e1; ++j) posb[j] = (unsigned short)t;
    }
    __syncthreads();
    for (int i = tid; i < n; i += 256) {
        int d = dst[base + i];
        int s = src[base + i];
        int b = d >> BSH;
        int p = atomicAdd(&cur2[b], 1);
        sedge[p] = ((unsigned int)s << BSH) | (unsigned int)(d & ((1 << BSH) - 1));
    }
    __syncthreads();
    for (int i = tid; i < n; i += 256) {
        int b = posb[i];
        bedge[gb[b] + (i - lbase[b])] = sedge[i];
    }
}

// ---------------- pass D: per-bucket CSR + degrees + dinv, all coalesced ----------------
__global__ __launch_bounds__(256) void bcsr_k(const unsigned int* __restrict__ bedge,
                                              const int* __restrict__ gbase,
                                              int* __restrict__ row_ptr, int* __restrict__ cnt,
                                              float* __restrict__ dinv, int* __restrict__ col,
                                              int N, int B) {
    __shared__ int hist[256], lofs[256], cur2[256];
    __shared__ int sa[256], sb[256];
    __shared__ int cols[CAP];
    int b = blockIdx.x, tid = threadIdx.x;
    int node0 = b << BSH;
    int g0 = gbase[b], g1 = gbase[b + 1];
    int n = g1 - g0;
    hist[tid] = 0;
    __syncthreads();
    for (int i = tid; i < n; i += 256) atomicAdd(&hist[bedge[g0 + i] & 255], 1);
    __syncthreads();
    sa[tid] = hist[tid];
    __syncthreads();
    int* c = sa; int* nx = sb;
    for (int off = 1; off < 256; off <<= 1) {
        nx[tid] = c[tid] + (tid >= off ? c[tid - off] : 0);
        __syncthreads();
        int* t = c; c = nx; nx = t;
    }
    int ex = c[tid] - hist[tid];
    lofs[tid] = ex; cur2[tid] = ex;
    int node = node0 + tid;
    if (node < N) {
        int deg = hist[tid];
        cnt[node] = deg;
        row_ptr[node] = g0 + ex;
        dinv[node] = rsqrtf((float)(deg + 1));
    }
    __syncthreads();
    for (int i = tid; i < n; i += 256) {
        unsigned int e = bedge[g0 + i];
        int p = atomicAdd(&cur2[e & 255], 1);
        if (p < CAP) cols[p] = (int)(e >> BSH);
    }
    __syncthreads();
    for (int i = tid; i < n; i += 256) col[g0 + i] = (i < CAP) ? cols[i] : 0;
}

// ---------------- graph boundaries from sorted batch ----------------
__global__ __launch_bounds__(256) void gbound_k(const int* __restrict__ batch, int* __restrict__ gstart,
                                                int N, int G) {
    int i = blockIdx.x * 256 + threadIdx.x;
    if (i >= N) return;
    int b = batch[i];
    int prev = (i == 0) ? -1 : batch[i - 1];
    for (int g = prev + 1; g <= b; ++g) gstart[g] = i;
    if (i == N - 1) {
        for (int g = b + 1; g <= G; ++g) gstart[g] = N;
    }
}

// ---------------- GEMM1: hs_h = fp16( dinv[r] * (x @ W1) ),  [N,128]@[128,64] ----------------
__global__ __launch_bounds__(256) void gemm1_k(const float* __restrict__ x, const float* __restrict__ W1,
                                               const float* __restrict__ dinv, h16* __restrict__ hsh, int N) {
    __shared__ float xT[128][64];   // k-major x tile
    __shared__ float wS[128][64];
    const int tid = threadIdx.x;
    const int row0 = blockIdx.x * 64;

    {   // W1: 8192 floats = 2048 f4, contiguous
        const f4* wsrc = (const f4*)W1;
        f4* wdst = (f4*)&wS[0][0];
        #pragma unroll
        for (int i = 0; i < 8; ++i) wdst[tid + i * 256] = wsrc[tid + i * 256];
    }
    {   // x tile rows row0..row0+63, transposed into LDS
        #pragma unroll
        for (int it = 0; it < 8; ++it) {
            int i = tid + it * 256;      // 0..2047
            int r = i & 63;
            int k4 = (i >> 6) * 4;       // 0..124
            int row = row0 + r;
            f4 v = (f4)(0.0f);
            if (row < N) v = *(const f4*)(x + (size_t)row * 128 + k4);
            xT[k4 + 0][r] = v.x; xT[k4 + 1][r] = v.y;
            xT[k4 + 2][r] = v.z; xT[k4 + 3][r] = v.w;
        }
    }
    __syncthreads();

    const int rl = (tid & 15) * 4;    // local rows rl..rl+3
    const int c0 = (tid >> 4) * 4;    // cols c0..c0+3
    f4 acc0 = (f4)(0.0f), acc1 = (f4)(0.0f), acc2 = (f4)(0.0f), acc3 = (f4)(0.0f);
    #pragma unroll 8
    for (int k = 0; k < 128; ++k) {
        f4 xa = *(const f4*)&xT[k][rl];
        f4 wb = *(const f4*)&wS[k][c0];
        acc0 += xa.x * wb;
        acc1 += xa.y * wb;
        acc2 += xa.z * wb;
        acc3 += xa.w * wb;
    }
    #pragma unroll
    for (int i = 0; i < 4; ++i) {
        int row = row0 + rl + i;
        if (row < N) {
            float di = dinv[row];
            f4 a = (i == 0) ? acc0 : (i == 1) ? acc1 : (i == 2) ? acc2 : acc3;
            a *= di;
            uint2 p;
            p.x = pack2h(a.x, a.y);
            p.y = pack2h(a.z, a.w);
            *(uint2*)(hsh + (size_t)row * 64 + c0) = p;
        }
    }
}

// ---------------- AGG1+GEMM2 fused (R15 best-measured): wave per node, dword (2 fp16 ch) per lane ----------------
// Gather: c2 = lane&31 -> channels 2c2,2c2+1; h = lane>>5 -> edge subgroup.
// 8-edge unroll: 4 independent loads in flight per subgroup.
__global__ __launch_bounds__(256) void agg1_k(const h16* __restrict__ hsh, const int* __restrict__ row_ptr,
                                              const int* __restrict__ cnt, const int* __restrict__ col,
                                              const float* __restrict__ dinv, const float* __restrict__ b1,
                                              const float* __restrict__ W2, h16* __restrict__ h2sh, int N) {
    int wid = blockIdx.x * 4 + (threadIdx.x >> 6);
    int lane = threadIdx.x & 63;
    if (wid >= N) return;
    const int c16 = lane & 15;      // output channel (for the fused dot)
    const int hh  = lane >> 4;      // k-quarter 0..3
    float wreg[16];
    #pragma unroll
    for (int k = 0; k < 16; ++k) wreg[k] = W2[(hh * 16 + k) * 16 + c16];
    float bias = b1[lane];

    const int c2 = lane & 31;       // channel pair index
    const int h  = lane >> 5;       // edge subgroup 0/1
    const uint32* rowbase = (const uint32*)hsh + c2;   // + s*32 dwords = row s, channels 2c2,2c2+1

    int beg = row_ptr[wid];
    int num = cnt[wid];
    float accx = 0.0f, accy = 0.0f;
    for (int e0 = 0; e0 < num; e0 += 64) {
        int rem = num - e0;
        int el = 0;
        if (lane < rem) el = col[beg + e0 + lane];
        int m = rem < 64 ? rem : 64;
        int e = 0;
        for (; e + 8 <= m; e += 8) {       // subgroup h: edges e+h, e+2+h, e+4+h, e+6+h (4 loads in flight)
            int s0 = __shfl(el, e + h);
            int s1 = __shfl(el, e + 2 + h);
            int s2 = __shfl(el, e + 4 + h);
            int s3 = __shfl(el, e + 6 + h);
            h2u u0, u1, u2, u3;
            u0.u = rowbase[(size_t)s0 * 32];
            u1.u = rowbase[(size_t)s1 * 32];
            u2.u = rowbase[(size_t)s2 * 32];
            u3.u = rowbase[(size_t)s3 * 32];
            accx += ((float)u0.h[0] + (float)u1.h[0]) + ((float)u2.h[0] + (float)u3.h[0]);
            accy += ((float)u0.h[1] + (float)u1.h[1]) + ((float)u2.h[1] + (float)u3.h[1]);
        }
        for (; e + 4 <= m; e += 4) {       // subgroup h: edges e+h, e+2+h
            int s0 = __shfl(el, e + h);
            int s1 = __shfl(el, e + 2 + h);
            h2u u0, u1;
            u0.u = rowbase[(size_t)s0 * 32];
            u1.u = rowbase[(size_t)s1 * 32];
            accx += (float)u0.h[0] + (float)u1.h[0];
            accy += (float)u0.h[1] + (float)u1.h[1];
        }
        for (; e + 2 <= m; e += 2) {       // subgroup h: edge e+h
            int s = __shfl(el, e + h);
            h2u u; u.u = rowbase[(size_t)s * 32];
            accx += (float)u.h[0];
            accy += (float)u.h[1];
        }
        if (e < m) {                       // single leftover edge: h==0 half covers all channels
            int s = __shfl(el, e);
            if (h == 0) {
                h2u u; u.u = rowbase[(size_t)s * 32];
                accx += (float)u.h[0];
                accy += (float)u.h[1];
            }
        }
    }
    // merge the two edge subgroups
    accx += __shfl_xor(accx, 32);
    accy += __shfl_xor(accy, 32);
    // redistribute channel pairs -> lane = channel
    float ra = __shfl(accx, lane >> 1);
    float rb = __shfl(accy, lane >> 1);
    float acc = (lane & 1) ? rb : ra;

    float di = dinv[wid];
    float self = (float)hsh[(size_t)wid * 64 + lane];
    float h1v = tanhf(di * (acc + self) + bias);

    // fused h1_row @ W2: lane (hh,c16) does k = hh*16..hh*16+15, then butterfly-add quarters
    float p = 0.0f;
    #pragma unroll
    for (int k = 0; k < 16; ++k) {
        float hv = __shfl(h1v, hh * 16 + k);
        p += hv * wreg[k];
    }
    p += __shfl_xor(p, 16);
    p += __shfl_xor(p, 32);
    if (lane < 16) h2sh[(size_t)wid * 16 + lane] = (h16)(di * p);
}

// ---------------- AGG2: 16 channels, quarter-wave per node, fp16 table (3.2MB -> L2-resident) ----------------
__global__ __launch_bounds__(256) void agg2_k(const h16* __restrict__ h2sh, const int* __restrict__ row_ptr,
                                              const int* __restrict__ cnt, const int* __restrict__ col,
                                              const float* __restrict__ dinv, const float* __restrict__ b2,
                                              float* __restrict__ h2, int N) {
    int t = blockIdx.x * 256 + threadIdx.x;
    int node = t >> 4;
    int c = t & 15;
    int sub = (threadIdx.x >> 4) & 3;   // quarter within wave
    if (node >= N) return;
    int beg = row_ptr[node];
    int num = cnt[node];
    float acc = 0.0f;
    for (int e0 = 0; e0 < num; e0 += 16) {
        int rem = num - e0;
        int el = 0;
        if (c < rem) el = col[beg + e0 + c];
        int m = rem < 16 ? rem : 16;
        int e = 0;
        for (; e + 4 <= m; e += 4) {       // 4 independent loads in flight
            int s0 = __shfl(el, (sub << 4) + e + 0);
            int s1 = __shfl(el, (sub << 4) + e + 1);
            int s2 = __shfl(el, (sub << 4) + e + 2);
            int s3 = __shfl(el, (sub << 4) + e + 3);
            float v0 = (float)h2sh[(size_t)s0 * 16 + c];
            float v1 = (float)h2sh[(size_t)s1 * 16 + c];
            float v2 = (float)h2sh[(size_t)s2 * 16 + c];
            float v3 = (float)h2sh[(size_t)s3 * 16 + c];
            acc += (v0 + v1) + (v2 + v3);
        }
        for (; e < m; ++e) {
            int s = __shfl(el, (sub << 4) + e);
            acc += (float)h2sh[(size_t)s * 16 + c];
        }
    }
    float di = dinv[node];
    float self = (float)h2sh[(size_t)node * 16 + c];
    h2[(size_t)node * 16 + c] = tanhf(di * (acc + self) + b2[c]);
}

// ---------------- segmented pool + sigmoid: one block per graph ----------------
__global__ __launch_bounds__(256) void pool_seg_k(const float* __restrict__ h2, const int* __restrict__ gstart,
                                                  float* __restrict__ out) {
    __shared__ float sd[16][16];   // [node-lane][channel]
    int g = blockIdx.x;
    int beg = gstart[g], end = gstart[g + 1];
    int tid = threadIdx.x;
    int c = tid & 15, r = tid >> 4;
    float acc = 0.0f;
    for (int i = beg + r; i < end; i += 16)
        acc += h2[(size_t)i * 16 + c];
    sd[r][c] = acc;
    __syncthreads();
    if (r < 8) sd[r][c] += sd[r + 8][c];
    __syncthreads();
    if (r < 4) sd[r][c] += sd[r + 4][c];
    __syncthreads();
    if (r < 2) sd[r][c] += sd[r + 2][c];
    __syncthreads();
    if (r == 0) {
        float m = (sd[0][c] + sd[1][c]) / fmaxf((float)(end - beg), 1.0f);
        out[g * 16 + c] = 1.0f / (1.0f + expf(-m));
    }
}

extern "C" void kernel_launch(void* const* d_in, const int* in_sizes, int n_in,
                              void* d_out, int out_size, void* d_ws, size_t ws_size,
                              hipStream_t stream) {
    const float* x     = (const float*)d_in[0];
    const int*   ei    = (const int*)d_in[1];
    const int*   batch = (const int*)d_in[2];
    const float* W1    = (const float*)d_in[3];
    const float* b1    = (const float*)d_in[4];
    const float* W2    = (const float*)d_in[5];
    const float* b2    = (const float*)d_in[6];
    float* out = (float*)d_out;

    const int N = in_sizes[2];
    const int E = in_sizes[1] / 2;
    const int G = out_size / 16;
    const int* src = ei;
    const int* dst = ei + E;

    const int B = (N + 255) >> 8;              // 391 buckets (must be <= 512)
    const int nchunk = (E + CHUNK - 1) / CHUNK;

    char* w = (char*)d_ws;
    int*   bcnt     = (int*)w;    w += 512 * 4;
    int*   gbase    = (int*)w;    w += 520 * 4;
    int*   gcur     = (int*)w;    w += 512 * 4;
    int*   row_ptr  = (int*)w;    w += (size_t)N * 4;
    int*   cnt      = (int*)w;    w += (size_t)N * 4;
    float* dinv     = (float*)w;  w += (size_t)N * 4;
    int*   gstart   = (int*)w;    w += 528 * 4;          // padded so hsh stays 8B-aligned
    int*   col      = (int*)w;    w += (size_t)E * 4;
    h16*   hsh      = (h16*)w;    w += (size_t)N * 64 * 2;
    h16*   h2sh     = (h16*)w;    w += (size_t)N * 16 * 2;
    float* h2       = (float*)w;  w += (size_t)N * 16 * 4;
    unsigned int* bedge = (unsigned int*)w;  w += (size_t)E * 4;

    hipMemsetAsync(bcnt, 0, 512 * 4, stream);

    bcount_k<<<nchunk, 256, 0, stream>>>(dst, bcnt, E, B);
    bscan_k <<<1, 256, 0, stream>>>(bcnt, gbase, gcur, B, E);
    bscat_k <<<nchunk, 256, 0, stream>>>(src, dst, gcur, bedge, E, B);
    bcsr_k  <<<B, 256, 0, stream>>>(bedge, gbase, row_ptr, cnt, dinv, col, N, B);
    gbound_k<<<(N + 255) / 256, 256, 0, stream>>>(batch, gstart, N, G);

    gemm1_k <<<(N + 63) / 64, 256, 0, stream>>>(x, W1, dinv, hsh, N);
    agg1_k  <<<(N + 3) / 4, 256, 0, stream>>>(hsh, row_ptr, cnt, col, dinv, b1, W2, h2sh, N);
    agg2_k  <<<((size_t)N * 16 + 255) / 256, 256, 0, stream>>>(h2sh, row_ptr, cnt, col, dinv, b2, h2, N);
    pool_seg_k<<<G, 256, 0, stream>>>(h2, gstart, out);
}

// Round 21
// 176.859 us; speedup vs baseline: 1.0936x; 1.0179x over previous
//
#include <hip/hip_runtime.h>
#include <hip/hip_bf16.h>

typedef float f4 __attribute__((ext_vector_type(4)));
typedef unsigned short us;
typedef unsigned int uint32;
typedef _Float16 h16;

union h2u { uint32 u; h16 h[2]; };
__device__ inline uint32 pack2h(float a, float b) { h2u x; x.h[0] = (h16)a; x.h[1] = (h16)b; return x.u; }

#define BSH 8            // 256 nodes per bucket
#define CHUNK 4096       // edges per sort workgroup
#define CAP 6144         // max edges per bucket (mean 4096, +32 sigma)

// ---------------- pass A: global bucket counts (+ fused gbound in extra blocks) ----------------
__global__ __launch_bounds__(256) void bcount_k(const int* __restrict__ dst, int* __restrict__ bcnt,
                                                const int* __restrict__ batch, int* __restrict__ gstart,
                                                int E, int B, int N, int G, int nchunk) {
    int tid = threadIdx.x;
    if (blockIdx.x >= nchunk) {   // gbound part
        int i = (blockIdx.x - nchunk) * 256 + tid;
        if (i >= N) return;
        int b = batch[i];
        int prev = (i == 0) ? -1 : batch[i - 1];
        for (int g = prev + 1; g <= b; ++g) gstart[g] = i;
        if (i == N - 1) {
            for (int g = b + 1; g <= G; ++g) gstart[g] = N;
        }
        return;
    }
    __shared__ int hist[512];
    for (int i = tid; i < 512; i += 256) hist[i] = 0;
    __syncthreads();
    int base = blockIdx.x * CHUNK;
    int n = min(CHUNK, E - base);
    for (int i = tid; i < n; i += 256) atomicAdd(&hist[dst[base + i] >> BSH], 1);
    __syncthreads();
    for (int i = tid; i < B; i += 256) if (hist[i]) atomicAdd(&bcnt[i], hist[i]);
}

// ---------------- pass B: exclusive scan of bucket counts (B <= 512) ----------------
__global__ __launch_bounds__(256) void bscan_k(const int* __restrict__ bcnt, int* __restrict__ gbase,
                                               int* __restrict__ gcur, int B, int E) {
    __shared__ int sa[512], sb[512];
    int tid = threadIdx.x;
    #pragma unroll
    for (int k = 0; k < 2; ++k) { int i = tid + k * 256; sa[i] = (i < B) ? bcnt[i] : 0; }
    __syncthreads();
    int* c = sa; int* nx = sb;
    for (int off = 1; off < 512; off <<= 1) {
        #pragma unroll
        for (int k = 0; k < 2; ++k) { int i = tid + k * 256; nx[i] = c[i] + (i >= off ? c[i - off] : 0); }
        __syncthreads();
        int* t = c; c = nx; nx = t;
    }
    #pragma unroll
    for (int k = 0; k < 2; ++k) {
        int i = tid + k * 256;
        if (i < B) { int ex = c[i] - bcnt[i]; gbase[i] = ex; gcur[i] = ex; }
    }
    if (tid == 0) gbase[B] = E;
}

// ---------------- pass C: chunked counting sort -> bucket-grouped packed edges ----------------
// bedge[pos] = (src << 8) | (dst & 255), grouped by bucket (dst >> 8). Requires src < 2^24.
__global__ __launch_bounds__(256) void bscat_k(const int* __restrict__ src, const int* __restrict__ dst,
                                               int* __restrict__ gcur, unsigned int* __restrict__ bedge,
                                               int E, int B) {
    __shared__ int hist[512], lbase[512], cur2[512], gb[512];
    __shared__ int sa[512], sb[512];
    __shared__ unsigned int sedge[CHUNK];
    __shared__ unsigned short posb[CHUNK];
    int tid = threadIdx.x;
    int base = blockIdx.x * CHUNK;
    int n = min(CHUNK, E - base);
    for (int i = tid; i < 512; i += 256) hist[i] = 0;
    __syncthreads();
    for (int i = tid; i < n; i += 256) atomicAdd(&hist[dst[base + i] >> BSH], 1);
    __syncthreads();
    #pragma unroll
    for (int k = 0; k < 2; ++k) { int i = tid + k * 256; sa[i] = hist[i]; }
    __syncthreads();
    int* c = sa; int* nx = sb;
    for (int off = 1; off < 512; off <<= 1) {
        #pragma unroll
        for (int k = 0; k < 2; ++k) { int i = tid + k * 256; nx[i] = c[i] + (i >= off ? c[i - off] : 0); }
        __syncthreads();
        int* t = c; c = nx; nx = t;
    }
    #pragma unroll
    for (int k = 0; k < 2; ++k) {
        int i = tid + k * 256;
        int ex = c[i] - hist[i];
        lbase[i] = ex; cur2[i] = ex;
        if (i < B) gb[i] = hist[i] ? atomicAdd(&gcur[i], hist[i]) : 0;
    }
    for (int t = tid; t < B; t += 256) {
        int e0 = lbase[t], e1 = e0 + hist[t];
        for (int j = e0; j < e1; ++j) posb[j] = (unsigned short)t;
    }
    __syncthreads();
    for (int i = tid; i < n; i += 256) {
        int d = dst[base + i];
        int s = src[base + i];
        int b = d >> BSH;
        int p = atomicAdd(&cur2[b], 1);
        sedge[p] = ((unsigned int)s << BSH) | (unsigned int)(d & ((1 << BSH) - 1));
    }
    __syncthreads();
    for (int i = tid; i < n; i += 256) {
        int b = posb[i];
        bedge[gb[b] + (i - lbase[b])] = sedge[i];
    }
}

// ---------------- pass D: per-bucket CSR + degrees + dinv, all coalesced ----------------
__global__ __launch_bounds__(256) void bcsr_k(const unsigned int* __restrict__ bedge,
                                              const int* __restrict__ gbase,
                                              int* __restrict__ row_ptr, int* __restrict__ cnt,
                                              float* __restrict__ dinv, int* __restrict__ col,
                                              int N, int B) {
    __shared__ int hist[256], lofs[256], cur2[256];
    __shared__ int sa[256], sb[256];
    __shared__ int cols[CAP];
    int b = blockIdx.x, tid = threadIdx.x;
    int node0 = b << BSH;
    int g0 = gbase[b], g1 = gbase[b + 1];
    int n = g1 - g0;
    hist[tid] = 0;
    __syncthreads();
    for (int i = tid; i < n; i += 256) atomicAdd(&hist[bedge[g0 + i] & 255], 1);
    __syncthreads();
    sa[tid] = hist[tid];
    __syncthreads();
    int* c = sa; int* nx = sb;
    for (int off = 1; off < 256; off <<= 1) {
        nx[tid] = c[tid] + (tid >= off ? c[tid - off] : 0);
        __syncthreads();
        int* t = c; c = nx; nx = t;
    }
    int ex = c[tid] - hist[tid];
    lofs[tid] = ex; cur2[tid] = ex;
    int node = node0 + tid;
    if (node < N) {
        int deg = hist[tid];
        cnt[node] = deg;
        row_ptr[node] = g0 + ex;
        dinv[node] = rsqrtf((float)(deg + 1));
    }
    __syncthreads();
    for (int i = tid; i < n; i += 256) {
        unsigned int e = bedge[g0 + i];
        int p = atomicAdd(&cur2[e & 255], 1);
        if (p < CAP) cols[p] = (int)(e >> BSH);
    }
    __syncthreads();
    for (int i = tid; i < n; i += 256) col[g0 + i] = (i < CAP) ? cols[i] : 0;
}

// ---------------- GEMM1: hs_h = fp16( dinv[r] * (x @ W1) ),  [N,128]@[128,64] ----------------
__global__ __launch_bounds__(256) void gemm1_k(const float* __restrict__ x, const float* __restrict__ W1,
                                               const float* __restrict__ dinv, h16* __restrict__ hsh, int N) {
    __shared__ float xT[128][64];   // k-major x tile
    __shared__ float wS[128][64];
    const int tid = threadIdx.x;
    const int row0 = blockIdx.x * 64;

    {   // W1: 8192 floats = 2048 f4, contiguous
        const f4* wsrc = (const f4*)W1;
        f4* wdst = (f4*)&wS[0][0];
        #pragma unroll
        for (int i = 0; i < 8; ++i) wdst[tid + i * 256] = wsrc[tid + i * 256];
    }
    {   // x tile rows row0..row0+63, transposed into LDS
        #pragma unroll
        for (int it = 0; it < 8; ++it) {
            int i = tid + it * 256;      // 0..2047
            int r = i & 63;
            int k4 = (i >> 6) * 4;       // 0..124
            int row = row0 + r;
            f4 v = (f4)(0.0f);
            if (row < N) v = *(const f4*)(x + (size_t)row * 128 + k4);
            xT[k4 + 0][r] = v.x; xT[k4 + 1][r] = v.y;
            xT[k4 + 2][r] = v.z; xT[k4 + 3][r] = v.w;
        }
    }
    __syncthreads();

    const int rl = (tid & 15) * 4;    // local rows rl..rl+3
    const int c0 = (tid >> 4) * 4;    // cols c0..c0+3
    f4 acc0 = (f4)(0.0f), acc1 = (f4)(0.0f), acc2 = (f4)(0.0f), acc3 = (f4)(0.0f);
    #pragma unroll 8
    for (int k = 0; k < 128; ++k) {
        f4 xa = *(const f4*)&xT[k][rl];
        f4 wb = *(const f4*)&wS[k][c0];
        acc0 += xa.x * wb;
        acc1 += xa.y * wb;
        acc2 += xa.z * wb;
        acc3 += xa.w * wb;
    }
    #pragma unroll
    for (int i = 0; i < 4; ++i) {
        int row = row0 + rl + i;
        if (row < N) {
            float di = dinv[row];
            f4 a = (i == 0) ? acc0 : (i == 1) ? acc1 : (i == 2) ? acc2 : acc3;
            a *= di;
            uint2 p;
            p.x = pack2h(a.x, a.y);
            p.y = pack2h(a.z, a.w);
            *(uint2*)(hsh + (size_t)row * 64 + c0) = p;
        }
    }
}

// ---------------- AGG1+GEMM2 fused: wave per node, dword (2 fp16 ch) per lane ----------------
// Gather: c2 = lane&31 -> channels 2c2,2c2+1; h = lane>>5 -> edge subgroup.
// 16-edge unroll: 8 independent loads in flight per subgroup.
__global__ __launch_bounds__(256) void agg1_k(const h16* __restrict__ hsh, const int* __restrict__ row_ptr,
                                              const int* __restrict__ cnt, const int* __restrict__ col,
                                              const float* __restrict__ dinv, const float* __restrict__ b1,
                                              const float* __restrict__ W2, h16* __restrict__ h2sh, int N) {
    int wid = blockIdx.x * 4 + (threadIdx.x >> 6);
    int lane = threadIdx.x & 63;
    if (wid >= N) return;
    const int c16 = lane & 15;      // output channel (for the fused dot)
    const int hh  = lane >> 4;      // k-quarter 0..3
    float wreg[16];
    #pragma unroll
    for (int k = 0; k < 16; ++k) wreg[k] = W2[(hh * 16 + k) * 16 + c16];
    float bias = b1[lane];

    const int c2 = lane & 31;       // channel pair index
    const int h  = lane >> 5;       // edge subgroup 0/1
    const uint32* rowbase = (const uint32*)hsh + c2;   // + s*32 dwords = row s, channels 2c2,2c2+1

    int beg = row_ptr[wid];
    int num = cnt[wid];
    float accx = 0.0f, accy = 0.0f;
    for (int e0 = 0; e0 < num; e0 += 64) {
        int rem = num - e0;
        int el = 0;
        if (lane < rem) el = col[beg + e0 + lane];
        int m = rem < 64 ? rem : 64;
        int e = 0;
        for (; e + 16 <= m; e += 16) {     // subgroup h: 8 edges, 8 loads in flight
            int s0 = __shfl(el, e + h);
            int s1 = __shfl(el, e + 2 + h);
            int s2 = __shfl(el, e + 4 + h);
            int s3 = __shfl(el, e + 6 + h);
            int s4 = __shfl(el, e + 8 + h);
            int s5 = __shfl(el, e + 10 + h);
            int s6 = __shfl(el, e + 12 + h);
            int s7 = __shfl(el, e + 14 + h);
            h2u u0, u1, u2, u3, u4, u5, u6, u7;
            u0.u = rowbase[(size_t)s0 * 32];
            u1.u = rowbase[(size_t)s1 * 32];
            u2.u = rowbase[(size_t)s2 * 32];
            u3.u = rowbase[(size_t)s3 * 32];
            u4.u = rowbase[(size_t)s4 * 32];
            u5.u = rowbase[(size_t)s5 * 32];
            u6.u = rowbase[(size_t)s6 * 32];
            u7.u = rowbase[(size_t)s7 * 32];
            accx += ((float)u0.h[0] + (float)u1.h[0]) + ((float)u2.h[0] + (float)u3.h[0]);
            accy += ((float)u0.h[1] + (float)u1.h[1]) + ((float)u2.h[1] + (float)u3.h[1]);
            accx += ((float)u4.h[0] + (float)u5.h[0]) + ((float)u6.h[0] + (float)u7.h[0]);
            accy += ((float)u4.h[1] + (float)u5.h[1]) + ((float)u6.h[1] + (float)u7.h[1]);
        }
        for (; e + 8 <= m; e += 8) {       // subgroup h: edges e+h, e+2+h, e+4+h, e+6+h
            int s0 = __shfl(el, e + h);
            int s1 = __shfl(el, e + 2 + h);
            int s2 = __shfl(el, e + 4 + h);
            int s3 = __shfl(el, e + 6 + h);
            h2u u0, u1, u2, u3;
            u0.u = rowbase[(size_t)s0 * 32];
            u1.u = rowbase[(size_t)s1 * 32];
            u2.u = rowbase[(size_t)s2 * 32];
            u3.u = rowbase[(size_t)s3 * 32];
            accx += ((float)u0.h[0] + (float)u1.h[0]) + ((float)u2.h[0] + (float)u3.h[0]);
            accy += ((float)u0.h[1] + (float)u1.h[1]) + ((float)u2.h[1] + (float)u3.h[1]);
        }
        for (; e + 4 <= m; e += 4) {       // subgroup h: edges e+h, e+2+h
            int s0 = __shfl(el, e + h);
            int s1 = __shfl(el, e + 2 + h);
            h2u u0, u1;
            u0.u = rowbase[(size_t)s0 * 32];
            u1.u = rowbase[(size_t)s1 * 32];
            accx += (float)u0.h[0] + (float)u1.h[0];
            accy += (float)u0.h[1] + (float)u1.h[1];
        }
        for (; e + 2 <= m; e += 2) {       // subgroup h: edge e+h
            int s = __shfl(el, e + h);
            h2u u; u.u = rowbase[(size_t)s * 32];
            accx += (float)u.h[0];
            accy += (float)u.h[1];
        }
        if (e < m) {                       // single leftover edge: h==0 half covers all channels
            int s = __shfl(el, e);
            if (h == 0) {
                h2u u; u.u = rowbase[(size_t)s * 32];
                accx += (float)u.h[0];
                accy += (float)u.h[1];
            }
        }
    }
    // merge the two edge subgroups
    accx += __shfl_xor(accx, 32);
    accy += __shfl_xor(accy, 32);
    // redistribute channel pairs -> lane = channel
    float ra = __shfl(accx, lane >> 1);
    float rb = __shfl(accy, lane >> 1);
    float acc = (lane & 1) ? rb : ra;

    float di = dinv[wid];
    float self = (float)hsh[(size_t)wid * 64 + lane];
    float h1v = tanhf(di * (acc + self) + bias);

    // fused h1_row @ W2: lane (hh,c16) does k = hh*16..hh*16+15, then butterfly-add quarters
    float p = 0.0f;
    #pragma unroll
    for (int k = 0; k < 16; ++k) {
        float hv = __shfl(h1v, hh * 16 + k);
        p += hv * wreg[k];
    }
    p += __shfl_xor(p, 16);
    p += __shfl_xor(p, 32);
    if (lane < 16) h2sh[(size_t)wid * 16 + lane] = (h16)(di * p);
}

// ---------------- AGG2: 16 channels, quarter-wave per node, fp16 tables both sides ----------------
__global__ __launch_bounds__(256) void agg2_k(const h16* __restrict__ h2sh, const int* __restrict__ row_ptr,
                                              const int* __restrict__ cnt, const int* __restrict__ col,
                                              const float* __restrict__ dinv, const float* __restrict__ b2,
                                              h16* __restrict__ h2h, int N) {
    int t = blockIdx.x * 256 + threadIdx.x;
    int node = t >> 4;
    int c = t & 15;
    int sub = (threadIdx.x >> 4) & 3;   // quarter within wave
    if (node >= N) return;
    int beg = row_ptr[node];
    int num = cnt[node];
    float acc = 0.0f;
    for (int e0 = 0; e0 < num; e0 += 16) {
        int rem = num - e0;
        int el = 0;
        if (c < rem) el = col[beg + e0 + c];
        int m = rem < 16 ? rem : 16;
        int e = 0;
        for (; e + 4 <= m; e += 4) {       // 4 independent loads in flight
            int s0 = __shfl(el, (sub << 4) + e + 0);
            int s1 = __shfl(el, (sub << 4) + e + 1);
            int s2 = __shfl(el, (sub << 4) + e + 2);
            int s3 = __shfl(el, (sub << 4) + e + 3);
            float v0 = (float)h2sh[(size_t)s0 * 16 + c];
            float v1 = (float)h2sh[(size_t)s1 * 16 + c];
            float v2 = (float)h2sh[(size_t)s2 * 16 + c];
            float v3 = (float)h2sh[(size_t)s3 * 16 + c];
            acc += (v0 + v1) + (v2 + v3);
        }
        for (; e < m; ++e) {
            int s = __shfl(el, (sub << 4) + e);
            acc += (float)h2sh[(size_t)s * 16 + c];
        }
    }
    float di = dinv[node];
    float self = (float)h2sh[(size_t)node * 16 + c];
    h2h[(size_t)node * 16 + c] = (h16)tanhf(di * (acc + self) + b2[c]);
}

// ---------------- segmented pool + sigmoid: one block per graph ----------------
__global__ __launch_bounds__(256) void pool_seg_k(const h16* __restrict__ h2h, const int* __restrict__ gstart,
                                                  float* __restrict__ out) {
    __shared__ float sd[16][16];   // [node-lane][channel]
    int g = blockIdx.x;
    int beg = gstart[g], end = gstart[g + 1];
    int tid = threadIdx.x;
    int c = tid & 15, r = tid >> 4;
    float acc = 0.0f;
    for (int i = beg + r; i < end; i += 16)
        acc += (float)h2h[(size_t)i * 16 + c];
    sd[r][c] = acc;
    __syncthreads();
    if (r < 8) sd[r][c] += sd[r + 8][c];
    __syncthreads();
    if (r < 4) sd[r][c] += sd[r + 4][c];
    __syncthreads();
    if (r < 2) sd[r][c] += sd[r + 2][c];
    __syncthreads();
    if (r == 0) {
        float m = (sd[0][c] + sd[1][c]) / fmaxf((float)(end - beg), 1.0f);
        out[g * 16 + c] = 1.0f / (1.0f + expf(-m));
    }
}

extern "C" void kernel_launch(void* const* d_in, const int* in_sizes, int n_in,
                              void* d_out, int out_size, void* d_ws, size_t ws_size,
                              hipStream_t stream) {
    const float* x     = (const float*)d_in[0];
    const int*   ei    = (const int*)d_in[1];
    const int*   batch = (const int*)d_in[2];
    const float* W1    = (const float*)d_in[3];
    const float* b1    = (const float*)d_in[4];
    const float* W2    = (const float*)d_in[5];
    const float* b2    = (const float*)d_in[6];
    float* out = (float*)d_out;

    const int N = in_sizes[2];
    const int E = in_sizes[1] / 2;
    const int G = out_size / 16;
    const int* src = ei;
    const int* dst = ei + E;

    const int B = (N + 255) >> 8;              // 391 buckets (must be <= 512)
    const int nchunk = (E + CHUNK - 1) / CHUNK;
    const int nbound = (N + 255) / 256;

    char* w = (char*)d_ws;
    int*   bcnt     = (int*)w;    w += 512 * 4;
    int*   gbase    = (int*)w;    w += 520 * 4;
    int*   gcur     = (int*)w;    w += 512 * 4;
    int*   row_ptr  = (int*)w;    w += (size_t)N * 4;
    int*   cnt      = (int*)w;    w += (size_t)N * 4;
    float* dinv     = (float*)w;  w += (size_t)N * 4;
    int*   gstart   = (int*)w;    w += 528 * 4;          // padded so hsh stays 8B-aligned
    int*   col      = (int*)w;    w += (size_t)E * 4;
    h16*   hsh      = (h16*)w;    w += (size_t)N * 64 * 2;
    h16*   h2sh     = (h16*)w;    w += (size_t)N * 16 * 2;
    h16*   h2h      = (h16*)w;    w += (size_t)N * 16 * 2;
    unsigned int* bedge = (unsigned int*)w;  w += (size_t)E * 4;

    hipMemsetAsync(bcnt, 0, 512 * 4, stream);

    bcount_k<<<nchunk + nbound, 256, 0, stream>>>(dst, bcnt, batch, gstart, E, B, N, G, nchunk);
    bscan_k <<<1, 256, 0, stream>>>(bcnt, gbase, gcur, B, E);
    bscat_k <<<nchunk, 256, 0, stream>>>(src, dst, gcur, bedge, E, B);
    bcsr_k  <<<B, 256, 0, stream>>>(bedge, gbase, row_ptr, cnt, dinv, col, N, B);

    gemm1_k <<<(N + 63) / 64, 256, 0, stream>>>(x, W1, dinv, hsh, N);
    agg1_k  <<<(N + 3) / 4, 256, 0, stream>>>(hsh, row_ptr, cnt, col, dinv, b1, W2, h2sh, N);
    agg2_k  <<<((size_t)N * 16 + 255) / 256, 256, 0, stream>>>(h2sh, row_ptr, cnt, col, dinv, b2, h2h, N);
    pool_seg_k<<<G, 256, 0, stream>>>(h2h, gstart, out);
}

// Round 22
// 175.754 us; speedup vs baseline: 1.1005x; 1.0063x over previous
//
#include <hip/hip_runtime.h>
#include <hip/hip_bf16.h>

typedef float f4 __attribute__((ext_vector_type(4)));
typedef unsigned short us;
typedef unsigned int uint32;
typedef _Float16 h16;
typedef _Float16 h16x2 __attribute__((ext_vector_type(2)));

union h2u { uint32 u; h16 h[2]; h16x2 v; };
__device__ inline uint32 pack2h(float a, float b) { h2u x; x.h[0] = (h16)a; x.h[1] = (h16)b; return x.u; }

#define BSH 8            // 256 nodes per bucket
#define CHUNK 4096       // edges per sort workgroup
#define CAP 6144         // max edges per bucket (mean 4096, +32 sigma)

// ---------------- pass A: global bucket counts (+ fused gbound in extra blocks) ----------------
__global__ __launch_bounds__(256) void bcount_k(const int* __restrict__ dst, int* __restrict__ bcnt,
                                                const int* __restrict__ batch, int* __restrict__ gstart,
                                                int E, int B, int N, int G, int nchunk) {
    int tid = threadIdx.x;
    if (blockIdx.x >= nchunk) {   // gbound part
        int i = (blockIdx.x - nchunk) * 256 + tid;
        if (i >= N) return;
        int b = batch[i];
        int prev = (i == 0) ? -1 : batch[i - 1];
        for (int g = prev + 1; g <= b; ++g) gstart[g] = i;
        if (i == N - 1) {
            for (int g = b + 1; g <= G; ++g) gstart[g] = N;
        }
        return;
    }
    __shared__ int hist[512];
    for (int i = tid; i < 512; i += 256) hist[i] = 0;
    __syncthreads();
    int base = blockIdx.x * CHUNK;
    int n = min(CHUNK, E - base);
    for (int i = tid; i < n; i += 256) atomicAdd(&hist[dst[base + i] >> BSH], 1);
    __syncthreads();
    for (int i = tid; i < B; i += 256) if (hist[i]) atomicAdd(&bcnt[i], hist[i]);
}

// ---------------- pass B: exclusive scan of bucket counts (B <= 512) ----------------
__global__ __launch_bounds__(256) void bscan_k(const int* __restrict__ bcnt, int* __restrict__ gbase,
                                               int* __restrict__ gcur, int B, int E) {
    __shared__ int sa[512], sb[512];
    int tid = threadIdx.x;
    #pragma unroll
    for (int k = 0; k < 2; ++k) { int i = tid + k * 256; sa[i] = (i < B) ? bcnt[i] : 0; }
    __syncthreads();
    int* c = sa; int* nx = sb;
    for (int off = 1; off < 512; off <<= 1) {
        #pragma unroll
        for (int k = 0; k < 2; ++k) { int i = tid + k * 256; nx[i] = c[i] + (i >= off ? c[i - off] : 0); }
        __syncthreads();
        int* t = c; c = nx; nx = t;
    }
    #pragma unroll
    for (int k = 0; k < 2; ++k) {
        int i = tid + k * 256;
        if (i < B) { int ex = c[i] - bcnt[i]; gbase[i] = ex; gcur[i] = ex; }
    }
    if (tid == 0) gbase[B] = E;
}

// ---------------- pass C: chunked counting sort -> bucket-grouped packed edges ----------------
// bedge[pos] = (src << 8) | (dst & 255), grouped by bucket (dst >> 8). Requires src < 2^24.
__global__ __launch_bounds__(256) void bscat_k(const int* __restrict__ src, const int* __restrict__ dst,
                                               int* __restrict__ gcur, unsigned int* __restrict__ bedge,
                                               int E, int B) {
    __shared__ int hist[512], lbase[512], cur2[512], gb[512];
    __shared__ int sa[512], sb[512];
    __shared__ unsigned int sedge[CHUNK];
    __shared__ unsigned short posb[CHUNK];
    int tid = threadIdx.x;
    int base = blockIdx.x * CHUNK;
    int n = min(CHUNK, E - base);
    for (int i = tid; i < 512; i += 256) hist[i] = 0;
    __syncthreads();
    for (int i = tid; i < n; i += 256) atomicAdd(&hist[dst[base + i] >> BSH], 1);
    __syncthreads();
    #pragma unroll
    for (int k = 0; k < 2; ++k) { int i = tid + k * 256; sa[i] = hist[i]; }
    __syncthreads();
    int* c = sa; int* nx = sb;
    for (int off = 1; off < 512; off <<= 1) {
        #pragma unroll
        for (int k = 0; k < 2; ++k) { int i = tid + k * 256; nx[i] = c[i] + (i >= off ? c[i - off] : 0); }
        __syncthreads();
        int* t = c; c = nx; nx = t;
    }
    #pragma unroll
    for (int k = 0; k < 2; ++k) {
        int i = tid + k * 256;
        int ex = c[i] - hist[i];
        lbase[i] = ex; cur2[i] = ex;
        if (i < B) gb[i] = hist[i] ? atomicAdd(&gcur[i], hist[i]) : 0;
    }
    for (int t = tid; t < B; t += 256) {
        int e0 = lbase[t], e1 = e0 + hist[t];
        for (int j = e0; j < e1; ++j) posb[j] = (unsigned short)t;
    }
    __syncthreads();
    for (int i = tid; i < n; i += 256) {
        int d = dst[base + i];
        int s = src[base + i];
        int b = d >> BSH;
        int p = atomicAdd(&cur2[b], 1);
        sedge[p] = ((unsigned int)s << BSH) | (unsigned int)(d & ((1 << BSH) - 1));
    }
    __syncthreads();
    for (int i = tid; i < n; i += 256) {
        int b = posb[i];
        bedge[gb[b] + (i - lbase[b])] = sedge[i];
    }
}

// ---------------- pass D: per-bucket CSR + degrees + dinv, all coalesced ----------------
__global__ __launch_bounds__(256) void bcsr_k(const unsigned int* __restrict__ bedge,
                                              const int* __restrict__ gbase,
                                              int* __restrict__ row_ptr, int* __restrict__ cnt,
                                              float* __restrict__ dinv, int* __restrict__ col,
                                              int N, int B) {
    __shared__ int hist[256], lofs[256], cur2[256];
    __shared__ int sa[256], sb[256];
    __shared__ int cols[CAP];
    int b = blockIdx.x, tid = threadIdx.x;
    int node0 = b << BSH;
    int g0 = gbase[b], g1 = gbase[b + 1];
    int n = g1 - g0;
    hist[tid] = 0;
    __syncthreads();
    for (int i = tid; i < n; i += 256) atomicAdd(&hist[bedge[g0 + i] & 255], 1);
    __syncthreads();
    sa[tid] = hist[tid];
    __syncthreads();
    int* c = sa; int* nx = sb;
    for (int off = 1; off < 256; off <<= 1) {
        nx[tid] = c[tid] + (tid >= off ? c[tid - off] : 0);
        __syncthreads();
        int* t = c; c = nx; nx = t;
    }
    int ex = c[tid] - hist[tid];
    lofs[tid] = ex; cur2[tid] = ex;
    int node = node0 + tid;
    if (node < N) {
        int deg = hist[tid];
        cnt[node] = deg;
        row_ptr[node] = g0 + ex;
        dinv[node] = rsqrtf((float)(deg + 1));
    }
    __syncthreads();
    for (int i = tid; i < n; i += 256) {
        unsigned int e = bedge[g0 + i];
        int p = atomicAdd(&cur2[e & 255], 1);
        if (p < CAP) cols[p] = (int)(e >> BSH);
    }
    __syncthreads();
    for (int i = tid; i < n; i += 256) col[g0 + i] = (i < CAP) ? cols[i] : 0;
}

// ---------------- GEMM1: hs_h = fp16( dinv[r] * (x @ W1) ),  [N,128]@[128,64] ----------------
__global__ __launch_bounds__(256) void gemm1_k(const float* __restrict__ x, const float* __restrict__ W1,
                                               const float* __restrict__ dinv, h16* __restrict__ hsh, int N) {
    __shared__ float xT[128][64];   // k-major x tile
    __shared__ float wS[128][64];
    const int tid = threadIdx.x;
    const int row0 = blockIdx.x * 64;

    {   // W1: 8192 floats = 2048 f4, contiguous
        const f4* wsrc = (const f4*)W1;
        f4* wdst = (f4*)&wS[0][0];
        #pragma unroll
        for (int i = 0; i < 8; ++i) wdst[tid + i * 256] = wsrc[tid + i * 256];
    }
    {   // x tile rows row0..row0+63, transposed into LDS
        #pragma unroll
        for (int it = 0; it < 8; ++it) {
            int i = tid + it * 256;      // 0..2047
            int r = i & 63;
            int k4 = (i >> 6) * 4;       // 0..124
            int row = row0 + r;
            f4 v = (f4)(0.0f);
            if (row < N) v = *(const f4*)(x + (size_t)row * 128 + k4);
            xT[k4 + 0][r] = v.x; xT[k4 + 1][r] = v.y;
            xT[k4 + 2][r] = v.z; xT[k4 + 3][r] = v.w;
        }
    }
    __syncthreads();

    const int rl = (tid & 15) * 4;    // local rows rl..rl+3
    const int c0 = (tid >> 4) * 4;    // cols c0..c0+3
    f4 acc0 = (f4)(0.0f), acc1 = (f4)(0.0f), acc2 = (f4)(0.0f), acc3 = (f4)(0.0f);
    #pragma unroll 8
    for (int k = 0; k < 128; ++k) {
        f4 xa = *(const f4*)&xT[k][rl];
        f4 wb = *(const f4*)&wS[k][c0];
        acc0 += xa.x * wb;
        acc1 += xa.y * wb;
        acc2 += xa.z * wb;
        acc3 += xa.w * wb;
    }
    #pragma unroll
    for (int i = 0; i < 4; ++i) {
        int row = row0 + rl + i;
        if (row < N) {
            float di = dinv[row];
            f4 a = (i == 0) ? acc0 : (i == 1) ? acc1 : (i == 2) ? acc2 : acc3;
            a *= di;
            uint2 p;
            p.x = pack2h(a.x, a.y);
            p.y = pack2h(a.z, a.w);
            *(uint2*)(hsh + (size_t)row * 64 + c0) = p;
        }
    }
}

// ---------------- AGG1+GEMM2 fused: wave per node, dword (2 fp16 ch) per lane ----------------
// 16-edge unroll, packed-fp16 tree accumulate per block (1 pk-add tree + 1 cvt pair per 8 loads).
__global__ __launch_bounds__(256) void agg1_k(const h16* __restrict__ hsh, const int* __restrict__ row_ptr,
                                              const int* __restrict__ cnt, const int* __restrict__ col,
                                              const float* __restrict__ dinv, const float* __restrict__ b1,
                                              const float* __restrict__ W2, h16* __restrict__ h2sh, int N) {
    int wid = blockIdx.x * 4 + (threadIdx.x >> 6);
    int lane = threadIdx.x & 63;
    if (wid >= N) return;
    const int c16 = lane & 15;      // output channel (for the fused dot)
    const int hh  = lane >> 4;      // k-quarter 0..3
    float wreg[16];
    #pragma unroll
    for (int k = 0; k < 16; ++k) wreg[k] = W2[(hh * 16 + k) * 16 + c16];
    float bias = b1[lane];

    const int c2 = lane & 31;       // channel pair index
    const int h  = lane >> 5;       // edge subgroup 0/1
    const uint32* rowbase = (const uint32*)hsh + c2;   // + s*32 dwords = row s, channels 2c2,2c2+1

    int beg = row_ptr[wid];
    int num = cnt[wid];
    float accx = 0.0f, accy = 0.0f;
    for (int e0 = 0; e0 < num; e0 += 64) {
        int rem = num - e0;
        int el = 0;
        if (lane < rem) el = col[beg + e0 + lane];
        int m = rem < 64 ? rem : 64;
        int e = 0;
        for (; e + 16 <= m; e += 16) {     // subgroup h: 8 edges; fp16 tree then one cvt pair
            int s0 = __shfl(el, e + h);
            int s1 = __shfl(el, e + 2 + h);
            int s2 = __shfl(el, e + 4 + h);
            int s3 = __shfl(el, e + 6 + h);
            int s4 = __shfl(el, e + 8 + h);
            int s5 = __shfl(el, e + 10 + h);
            int s6 = __shfl(el, e + 12 + h);
            int s7 = __shfl(el, e + 14 + h);
            h2u u0, u1, u2, u3, u4, u5, u6, u7;
            u0.u = rowbase[(size_t)s0 * 32];
            u1.u = rowbase[(size_t)s1 * 32];
            u2.u = rowbase[(size_t)s2 * 32];
            u3.u = rowbase[(size_t)s3 * 32];
            u4.u = rowbase[(size_t)s4 * 32];
            u5.u = rowbase[(size_t)s5 * 32];
            u6.u = rowbase[(size_t)s6 * 32];
            u7.u = rowbase[(size_t)s7 * 32];
            h2x: ;
            h16x2 t01 = u0.v + u1.v;
            h16x2 t23 = u2.v + u3.v;
            h16x2 t45 = u4.v + u5.v;
            h16x2 t67 = u6.v + u7.v;
            h16x2 t03 = t01 + t23;
            h16x2 t47 = t45 + t67;
            h16x2 tt  = t03 + t47;
            accx += (float)tt[0];
            accy += (float)tt[1];
        }
        for (; e + 8 <= m; e += 8) {       // subgroup h: 4 edges
            int s0 = __shfl(el, e + h);
            int s1 = __shfl(el, e + 2 + h);
            int s2 = __shfl(el, e + 4 + h);
            int s3 = __shfl(el, e + 6 + h);
            h2u u0, u1, u2, u3;
            u0.u = rowbase[(size_t)s0 * 32];
            u1.u = rowbase[(size_t)s1 * 32];
            u2.u = rowbase[(size_t)s2 * 32];
            u3.u = rowbase[(size_t)s3 * 32];
            accx += ((float)u0.h[0] + (float)u1.h[0]) + ((float)u2.h[0] + (float)u3.h[0]);
            accy += ((float)u0.h[1] + (float)u1.h[1]) + ((float)u2.h[1] + (float)u3.h[1]);
        }
        for (; e + 4 <= m; e += 4) {       // subgroup h: edges e+h, e+2+h
            int s0 = __shfl(el, e + h);
            int s1 = __shfl(el, e + 2 + h);
            h2u u0, u1;
            u0.u = rowbase[(size_t)s0 * 32];
            u1.u = rowbase[(size_t)s1 * 32];
            accx += (float)u0.h[0] + (float)u1.h[0];
            accy += (float)u0.h[1] + (float)u1.h[1];
        }
        for (; e + 2 <= m; e += 2) {       // subgroup h: edge e+h
            int s = __shfl(el, e + h);
            h2u u; u.u = rowbase[(size_t)s * 32];
            accx += (float)u.h[0];
            accy += (float)u.h[1];
        }
        if (e < m) {                       // single leftover edge: h==0 half covers all channels
            int s = __shfl(el, e);
            if (h == 0) {
                h2u u; u.u = rowbase[(size_t)s * 32];
                accx += (float)u.h[0];
                accy += (float)u.h[1];
            }
        }
    }
    // merge the two edge subgroups
    accx += __shfl_xor(accx, 32);
    accy += __shfl_xor(accy, 32);
    // redistribute channel pairs -> lane = channel
    float ra = __shfl(accx, lane >> 1);
    float rb = __shfl(accy, lane >> 1);
    float acc = (lane & 1) ? rb : ra;

    float di = dinv[wid];
    float self = (float)hsh[(size_t)wid * 64 + lane];
    float h1v = tanhf(di * (acc + self) + bias);

    // fused h1_row @ W2: lane (hh,c16) does k = hh*16..hh*16+15, then butterfly-add quarters
    float p = 0.0f;
    #pragma unroll
    for (int k = 0; k < 16; ++k) {
        float hv = __shfl(h1v, hh * 16 + k);
        p += hv * wreg[k];
    }
    p += __shfl_xor(p, 16);
    p += __shfl_xor(p, 32);
    if (lane < 16) h2sh[(size_t)wid * 16 + lane] = (h16)(di * p);
}

// ---------------- AGG2: 16 channels, quarter-wave per node, fp16 tables both sides ----------------
__global__ __launch_bounds__(256) void agg2_k(const h16* __restrict__ h2sh, const int* __restrict__ row_ptr,
                                              const int* __restrict__ cnt, const int* __restrict__ col,
                                              const float* __restrict__ dinv, const float* __restrict__ b2,
                                              h16* __restrict__ h2h, int N) {
    int t = blockIdx.x * 256 + threadIdx.x;
    int node = t >> 4;
    int c = t & 15;
    int sub = (threadIdx.x >> 4) & 3;   // quarter within wave
    if (node >= N) return;
    int beg = row_ptr[node];
    int num = cnt[node];
    float acc = 0.0f;
    for (int e0 = 0; e0 < num; e0 += 16) {
        int rem = num - e0;
        int el = 0;
        if (c < rem) el = col[beg + e0 + c];
        int m = rem < 16 ? rem : 16;
        int e = 0;
        for (; e + 4 <= m; e += 4) {       // 4 independent loads in flight
            int s0 = __shfl(el, (sub << 4) + e + 0);
            int s1 = __shfl(el, (sub << 4) + e + 1);
            int s2 = __shfl(el, (sub << 4) + e + 2);
            int s3 = __shfl(el, (sub << 4) + e + 3);
            float v0 = (float)h2sh[(size_t)s0 * 16 + c];
            float v1 = (float)h2sh[(size_t)s1 * 16 + c];
            float v2 = (float)h2sh[(size_t)s2 * 16 + c];
            float v3 = (float)h2sh[(size_t)s3 * 16 + c];
            acc += (v0 + v1) + (v2 + v3);
        }
        for (; e < m; ++e) {
            int s = __shfl(el, (sub << 4) + e);
            acc += (float)h2sh[(size_t)s * 16 + c];
        }
    }
    float di = dinv[node];
    float self = (float)h2sh[(size_t)node * 16 + c];
    h2h[(size_t)node * 16 + c] = (h16)tanhf(di * (acc + self) + b2[c]);
}

// ---------------- segmented pool + sigmoid: one block per graph ----------------
__global__ __launch_bounds__(256) void pool_seg_k(const h16* __restrict__ h2h, const int* __restrict__ gstart,
                                                  float* __restrict__ out) {
    __shared__ float sd[16][16];   // [node-lane][channel]
    int g = blockIdx.x;
    int beg = gstart[g], end = gstart[g + 1];
    int tid = threadIdx.x;
    int c = tid & 15, r = tid >> 4;
    float acc = 0.0f;
    for (int i = beg + r; i < end; i += 16)
        acc += (float)h2h[(size_t)i * 16 + c];
    sd[r][c] = acc;
    __syncthreads();
    if (r < 8) sd[r][c] += sd[r + 8][c];
    __syncthreads();
    if (r < 4) sd[r][c] += sd[r + 4][c];
    __syncthreads();
    if (r < 2) sd[r][c] += sd[r + 2][c];
    __syncthreads();
    if (r == 0) {
        float m = (sd[0][c] + sd[1][c]) / fmaxf((float)(end - beg), 1.0f);
        out[g * 16 + c] = 1.0f / (1.0f + expf(-m));
    }
}

extern "C" void kernel_launch(void* const* d_in, const int* in_sizes, int n_in,
                              void* d_out, int out_size, void* d_ws, size_t ws_size,
                              hipStream_t stream) {
    const float* x     = (const float*)d_in[0];
    const int*   ei    = (const int*)d_in[1];
    const int*   batch = (const int*)d_in[2];
    const float* W1    = (const float*)d_in[3];
    const float* b1    = (const float*)d_in[4];
    const float* W2    = (const float*)d_in[5];
    const float* b2    = (const float*)d_in[6];
    float* out = (float*)d_out;

    const int N = in_sizes[2];
    const int E = in_sizes[1] / 2;
    const int G = out_size / 16;
    const int* src = ei;
    const int* dst = ei + E;

    const int B = (N + 255) >> 8;              // 391 buckets (must be <= 512)
    const int nchunk = (E + CHUNK - 1) / CHUNK;
    const int nbound = (N + 255) / 256;

    char* w = (char*)d_ws;
    int*   bcnt     = (int*)w;    w += 512 * 4;
    int*   gbase    = (int*)w;    w += 520 * 4;
    int*   gcur     = (int*)w;    w += 512 * 4;
    int*   row_ptr  = (int*)w;    w += (size_t)N * 4;
    int*   cnt      = (int*)w;    w += (size_t)N * 4;
    float* dinv     = (float*)w;  w += (size_t)N * 4;
    int*   gstart   = (int*)w;    w += 528 * 4;          // padded so hsh stays 8B-aligned
    int*   col      = (int*)w;    w += (size_t)E * 4;
    h16*   hsh      = (h16*)w;    w += (size_t)N * 64 * 2;
    h16*   h2sh     = (h16*)w;    w += (size_t)N * 16 * 2;
    h16*   h2h      = (h16*)w;    w += (size_t)N * 16 * 2;
    unsigned int* bedge = (unsigned int*)w;  w += (size_t)E * 4;

    hipMemsetAsync(bcnt, 0, 512 * 4, stream);

    bcount_k<<<nchunk + nbound, 256, 0, stream>>>(dst, bcnt, batch, gstart, E, B, N, G, nchunk);
    bscan_k <<<1, 256, 0, stream>>>(bcnt, gbase, gcur, B, E);
    bscat_k <<<nchunk, 256, 0, stream>>>(src, dst, gcur, bedge, E, B);
    bcsr_k  <<<B, 256, 0, stream>>>(bedge, gbase, row_ptr, cnt, dinv, col, N, B);

    gemm1_k <<<(N + 63) / 64, 256, 0, stream>>>(x, W1, dinv, hsh, N);
    agg1_k  <<<(N + 3) / 4, 256, 0, stream>>>(hsh, row_ptr, cnt, col, dinv, b1, W2, h2sh, N);
    agg2_k  <<<((size_t)N * 16 + 255) / 256, 256, 0, stream>>>(h2sh, row_ptr, cnt, col, dinv, b2, h2h, N);
    pool_seg_k<<<G, 256, 0, stream>>>(h2h, gstart, out);
}

// Round 24
// 160.005 us; speedup vs baseline: 1.2088x; 1.0984x over previous
//
#include <hip/hip_runtime.h>
#include <hip/hip_bf16.h>

typedef float f4 __attribute__((ext_vector_type(4)));
typedef unsigned short us;
typedef unsigned int uint32;
typedef _Float16 h16;
typedef _Float16 h16x2 __attribute__((ext_vector_type(2)));

union h2u { uint32 u; h16 h[2]; h16x2 v; };
__device__ inline uint32 pack2h(float a, float b) { h2u x; x.h[0] = (h16)a; x.h[1] = (h16)b; return x.u; }

#define BSH 8            // 256 nodes per bucket
#define CHUNK 4096       // edges per sort workgroup
#define CAP 6144         // max edges per bucket (mean 4096, +32 sigma); also the fixed bucket stride

// ---------------- pass C (fused): chunk hist + LDS sort + padded-bucket placement (+ gbound blocks) ----------------
// bedge[b*CAP + i] = (src << 8) | (dst & 255). No global scan needed: buckets are fixed-stride.
__global__ __launch_bounds__(256) void bscat_k(const int* __restrict__ src, const int* __restrict__ dst,
                                               int* __restrict__ bcur, unsigned int* __restrict__ bedge,
                                               const int* __restrict__ batch, int* __restrict__ gstart,
                                               int E, int B, int N, int G, int nchunk) {
    int tid = threadIdx.x;
    if (blockIdx.x >= nchunk) {   // gbound part
        int i = (blockIdx.x - nchunk) * 256 + tid;
        if (i >= N) return;
        int b = batch[i];
        int prev = (i == 0) ? -1 : batch[i - 1];
        for (int g = prev + 1; g <= b; ++g) gstart[g] = i;
        if (i == N - 1) {
            for (int g = b + 1; g <= G; ++g) gstart[g] = N;
        }
        return;
    }
    __shared__ int hist[512], lbase[512], cur2[512], gb[512];
    __shared__ int sa[512], sb[512];
    __shared__ unsigned int sedge[CHUNK];
    __shared__ unsigned short posb[CHUNK];
    int base = blockIdx.x * CHUNK;
    int n = min(CHUNK, E - base);
    for (int i = tid; i < 512; i += 256) hist[i] = 0;
    __syncthreads();
    for (int i = tid; i < n; i += 256) atomicAdd(&hist[dst[base + i] >> BSH], 1);
    __syncthreads();
    #pragma unroll
    for (int k = 0; k < 2; ++k) { int i = tid + k * 256; sa[i] = hist[i]; }
    __syncthreads();
    int* c = sa; int* nx = sb;
    for (int off = 1; off < 512; off <<= 1) {
        #pragma unroll
        for (int k = 0; k < 2; ++k) { int i = tid + k * 256; nx[i] = c[i] + (i >= off ? c[i - off] : 0); }
        __syncthreads();
        int* t = c; c = nx; nx = t;
    }
    #pragma unroll
    for (int k = 0; k < 2; ++k) {
        int i = tid + k * 256;
        int ex = c[i] - hist[i];
        lbase[i] = ex; cur2[i] = ex;
        if (i < B) gb[i] = hist[i] ? (i * CAP + atomicAdd(&bcur[i], hist[i])) : 0;
    }
    for (int t = tid; t < B; t += 256) {
        int e0 = lbase[t], e1 = e0 + hist[t];
        for (int j = e0; j < e1; ++j) posb[j] = (unsigned short)t;
    }
    __syncthreads();
    for (int i = tid; i < n; i += 256) {
        int d = dst[base + i];
        int s = src[base + i];
        int b = d >> BSH;
        int p = atomicAdd(&cur2[b], 1);
        sedge[p] = ((unsigned int)s << BSH) | (unsigned int)(d & ((1 << BSH) - 1));
    }
    __syncthreads();
    for (int i = tid; i < n; i += 256) {
        int b = posb[i];
        bedge[gb[b] + (i - lbase[b])] = sedge[i];
    }
}

// ---------------- pass D: per-bucket CSR + degrees + dinv from padded buckets ----------------
__global__ __launch_bounds__(256) void bcsr_k(const unsigned int* __restrict__ bedge,
                                              const int* __restrict__ bcur,
                                              int* __restrict__ row_ptr, int* __restrict__ cnt,
                                              float* __restrict__ dinv, int* __restrict__ col,
                                              int N, int B) {
    __shared__ int hist[256], lofs[256], cur2[256];
    __shared__ int sa[256], sb[256];
    __shared__ int cols[CAP];
    int b = blockIdx.x, tid = threadIdx.x;
    int node0 = b << BSH;
    int g0 = b * CAP;
    int n = min(bcur[b], CAP);
    hist[tid] = 0;
    __syncthreads();
    for (int i = tid; i < n; i += 256) atomicAdd(&hist[bedge[g0 + i] & 255], 1);
    __syncthreads();
    sa[tid] = hist[tid];
    __syncthreads();
    int* c = sa; int* nx = sb;
    for (int off = 1; off < 256; off <<= 1) {
        nx[tid] = c[tid] + (tid >= off ? c[tid - off] : 0);
        __syncthreads();
        int* t = c; c = nx; nx = t;
    }
    int ex = c[tid] - hist[tid];
    lofs[tid] = ex; cur2[tid] = ex;
    int node = node0 + tid;
    if (node < N) {
        int deg = hist[tid];
        cnt[node] = deg;
        row_ptr[node] = g0 + ex;
        dinv[node] = rsqrtf((float)(deg + 1));
    }
    __syncthreads();
    for (int i = tid; i < n; i += 256) {
        unsigned int e = bedge[g0 + i];
        int p = atomicAdd(&cur2[e & 255], 1);
        if (p < CAP) cols[p] = (int)(e >> BSH);
    }
    __syncthreads();
    for (int i = tid; i < n; i += 256) col[g0 + i] = (i < CAP) ? cols[i] : 0;
}

// ---------------- GEMM1: hs_h = fp16( dinv[r] * (x @ W1) ),  [N,128]@[128,64] ----------------
__global__ __launch_bounds__(256) void gemm1_k(const float* __restrict__ x, const float* __restrict__ W1,
                                               const float* __restrict__ dinv, h16* __restrict__ hsh, int N) {
    __shared__ float xT[128][64];   // k-major x tile
    __shared__ float wS[128][64];
    const int tid = threadIdx.x;
    const int row0 = blockIdx.x * 64;

    {   // W1: 8192 floats = 2048 f4, contiguous
        const f4* wsrc = (const f4*)W1;
        f4* wdst = (f4*)&wS[0][0];
        #pragma unroll
        for (int i = 0; i < 8; ++i) wdst[tid + i * 256] = wsrc[tid + i * 256];
    }
    {   // x tile rows row0..row0+63, transposed into LDS
        #pragma unroll
        for (int it = 0; it < 8; ++it) {
            int i = tid + it * 256;      // 0..2047
            int r = i & 63;
            int k4 = (i >> 6) * 4;       // 0..124
            int row = row0 + r;
            f4 v = (f4)(0.0f);
            if (row < N) v = *(const f4*)(x + (size_t)row * 128 + k4);
            xT[k4 + 0][r] = v.x; xT[k4 + 1][r] = v.y;
            xT[k4 + 2][r] = v.z; xT[k4 + 3][r] = v.w;
        }
    }
    __syncthreads();

    const int rl = (tid & 15) * 4;    // local rows rl..rl+3
    const int c0 = (tid >> 4) * 4;    // cols c0..c0+3
    f4 acc0 = (f4)(0.0f), acc1 = (f4)(0.0f), acc2 = (f4)(0.0f), acc3 = (f4)(0.0f);
    #pragma unroll 8
    for (int k = 0; k < 128; ++k) {
        f4 xa = *(const f4*)&xT[k][rl];
        f4 wb = *(const f4*)&wS[k][c0];
        acc0 += xa.x * wb;
        acc1 += xa.y * wb;
        acc2 += xa.z * wb;
        acc3 += xa.w * wb;
    }
    #pragma unroll
    for (int i = 0; i < 4; ++i) {
        int row = row0 + rl + i;
        if (row < N) {
            float di = dinv[row];
            f4 a = (i == 0) ? acc0 : (i == 1) ? acc1 : (i == 2) ? acc2 : acc3;
            a *= di;
            uint2 p;
            p.x = pack2h(a.x, a.y);
            p.y = pack2h(a.z, a.w);
            *(uint2*)(hsh + (size_t)row * 64 + c0) = p;
        }
    }
}

// ---------------- AGG1+GEMM2 fused: wave per node, dword (2 fp16 ch) per lane ----------------
// 16-edge unroll, packed-fp16 tree accumulate per block.
__global__ __launch_bounds__(256) void agg1_k(const h16* __restrict__ hsh, const int* __restrict__ row_ptr,
                                              const int* __restrict__ cnt, const int* __restrict__ col,
                                              const float* __restrict__ dinv, const float* __restrict__ b1,
                                              const float* __restrict__ W2, h16* __restrict__ h2sh, int N) {
    int wid = blockIdx.x * 4 + (threadIdx.x >> 6);
    int lane = threadIdx.x & 63;
    if (wid >= N) return;
    const int c16 = lane & 15;      // output channel (for the fused dot)
    const int hh  = lane >> 4;      // k-quarter 0..3
    float wreg[16];
    #pragma unroll
    for (int k = 0; k < 16; ++k) wreg[k] = W2[(hh * 16 + k) * 16 + c16];
    float bias = b1[lane];

    const int c2 = lane & 31;       // channel pair index
    const int h  = lane >> 5;       // edge subgroup 0/1
    const uint32* rowbase = (const uint32*)hsh + c2;   // + s*32 dwords = row s, channels 2c2,2c2+1

    int beg = row_ptr[wid];
    int num = cnt[wid];
    float accx = 0.0f, accy = 0.0f;
    for (int e0 = 0; e0 < num; e0 += 64) {
        int rem = num - e0;
        int el = 0;
        if (lane < rem) el = col[beg + e0 + lane];
        int m = rem < 64 ? rem : 64;
        int e = 0;
        for (; e + 16 <= m; e += 16) {     // subgroup h: 8 edges; fp16 tree then one cvt pair
            int s0 = __shfl(el, e + h);
            int s1 = __shfl(el, e + 2 + h);
            int s2 = __shfl(el, e + 4 + h);
            int s3 = __shfl(el, e + 6 + h);
            int s4 = __shfl(el, e + 8 + h);
            int s5 = __shfl(el, e + 10 + h);
            int s6 = __shfl(el, e + 12 + h);
            int s7 = __shfl(el, e + 14 + h);
            h2u u0, u1, u2, u3, u4, u5, u6, u7;
            u0.u = rowbase[(size_t)s0 * 32];
            u1.u = rowbase[(size_t)s1 * 32];
            u2.u = rowbase[(size_t)s2 * 32];
            u3.u = rowbase[(size_t)s3 * 32];
            u4.u = rowbase[(size_t)s4 * 32];
            u5.u = rowbase[(size_t)s5 * 32];
            u6.u = rowbase[(size_t)s6 * 32];
            u7.u = rowbase[(size_t)s7 * 32];
            h16x2 t01 = u0.v + u1.v;
            h16x2 t23 = u2.v + u3.v;
            h16x2 t45 = u4.v + u5.v;
            h16x2 t67 = u6.v + u7.v;
            h16x2 t03 = t01 + t23;
            h16x2 t47 = t45 + t67;
            h16x2 tt  = t03 + t47;
            accx += (float)tt[0];
            accy += (float)tt[1];
        }
        for (; e + 8 <= m; e += 8) {       // subgroup h: 4 edges
            int s0 = __shfl(el, e + h);
            int s1 = __shfl(el, e + 2 + h);
            int s2 = __shfl(el, e + 4 + h);
            int s3 = __shfl(el, e + 6 + h);
            h2u u0, u1, u2, u3;
            u0.u = rowbase[(size_t)s0 * 32];
            u1.u = rowbase[(size_t)s1 * 32];
            u2.u = rowbase[(size_t)s2 * 32];
            u3.u = rowbase[(size_t)s3 * 32];
            accx += ((float)u0.h[0] + (float)u1.h[0]) + ((float)u2.h[0] + (float)u3.h[0]);
            accy += ((float)u0.h[1] + (float)u1.h[1]) + ((float)u2.h[1] + (float)u3.h[1]);
        }
        for (; e + 4 <= m; e += 4) {       // subgroup h: edges e+h, e+2+h
            int s0 = __shfl(el, e + h);
            int s1 = __shfl(el, e + 2 + h);
            h2u u0, u1;
            u0.u = rowbase[(size_t)s0 * 32];
            u1.u = rowbase[(size_t)s1 * 32];
            accx += (float)u0.h[0] + (float)u1.h[0];
            accy += (float)u0.h[1] + (float)u1.h[1];
        }
        for (; e + 2 <= m; e += 2) {       // subgroup h: edge e+h
            int s = __shfl(el, e + h);
            h2u u; u.u = rowbase[(size_t)s * 32];
            accx += (float)u.h[0];
            accy += (float)u.h[1];
        }
        if (e < m) {                       // single leftover edge: h==0 half covers all channels
            int s = __shfl(el, e);
            if (h == 0) {
                h2u u; u.u = rowbase[(size_t)s * 32];
                accx += (float)u.h[0];
                accy += (float)u.h[1];
            }
        }
    }
    // merge the two edge subgroups
    accx += __shfl_xor(accx, 32);
    accy += __shfl_xor(accy, 32);
    // redistribute channel pairs -> lane = channel
    float ra = __shfl(accx, lane >> 1);
    float rb = __shfl(accy, lane >> 1);
    float acc = (lane & 1) ? rb : ra;

    float di = dinv[wid];
    float self = (float)hsh[(size_t)wid * 64 + lane];
    float h1v = tanhf(di * (acc + self) + bias);

    // fused h1_row @ W2: lane (hh,c16) does k = hh*16..hh*16+15, then butterfly-add quarters
    float p = 0.0f;
    #pragma unroll
    for (int k = 0; k < 16; ++k) {
        float hv = __shfl(h1v, hh * 16 + k);
        p += hv * wreg[k];
    }
    p += __shfl_xor(p, 16);
    p += __shfl_xor(p, 32);
    if (lane < 16) h2sh[(size_t)wid * 16 + lane] = (h16)(di * p);
}

// ---------------- AGG2: 16 channels, quarter-wave per node, fp16 tables both sides ----------------
__global__ __launch_bounds__(256) void agg2_k(const h16* __restrict__ h2sh, const int* __restrict__ row_ptr,
                                              const int* __restrict__ cnt, const int* __restrict__ col,
                                              const float* __restrict__ dinv, const float* __restrict__ b2,
                                              h16* __restrict__ h2h, int N) {
    int t = blockIdx.x * 256 + threadIdx.x;
    int node = t >> 4;
    int c = t & 15;
    int sub = (threadIdx.x >> 4) & 3;   // quarter within wave
    if (node >= N) return;
    int beg = row_ptr[node];
    int num = cnt[node];
    float acc = 0.0f;
    for (int e0 = 0; e0 < num; e0 += 16) {
        int rem = num - e0;
        int el = 0;
        if (c < rem) el = col[beg + e0 + c];
        int m = rem < 16 ? rem : 16;
        int e = 0;
        for (; e + 4 <= m; e += 4) {       // 4 independent loads in flight
            int s0 = __shfl(el, (sub << 4) + e + 0);
            int s1 = __shfl(el, (sub << 4) + e + 1);
            int s2 = __shfl(el, (sub << 4) + e + 2);
            int s3 = __shfl(el, (sub << 4) + e + 3);
            float v0 = (float)h2sh[(size_t)s0 * 16 + c];
            float v1 = (float)h2sh[(size_t)s1 * 16 + c];
            float v2 = (float)h2sh[(size_t)s2 * 16 + c];
            float v3 = (float)h2sh[(size_t)s3 * 16 + c];
            acc += (v0 + v1) + (v2 + v3);
        }
        for (; e < m; ++e) {
            int s = __shfl(el, (sub << 4) + e);
            acc += (float)h2sh[(size_t)s * 16 + c];
        }
    }
    float di = dinv[node];
    float self = (float)h2sh[(size_t)node * 16 + c];
    h2h[(size_t)node * 16 + c] = (h16)tanhf(di * (acc + self) + b2[c]);
}

// ---------------- segmented pool + sigmoid: one block per graph ----------------
__global__ __launch_bounds__(256) void pool_seg_k(const h16* __restrict__ h2h, const int* __restrict__ gstart,
                                                  float* __restrict__ out) {
    __shared__ float sd[16][16];   // [node-lane][channel]
    int g = blockIdx.x;
    int beg = gstart[g], end = gstart[g + 1];
    int tid = threadIdx.x;
    int c = tid & 15, r = tid >> 4;
    float acc = 0.0f;
    for (int i = beg + r; i < end; i += 16)
        acc += (float)h2h[(size_t)i * 16 + c];
    sd[r][c] = acc;
    __syncthreads();
    if (r < 8) sd[r][c] += sd[r + 8][c];
    __syncthreads();
    if (r < 4) sd[r][c] += sd[r + 4][c];
    __syncthreads();
    if (r < 2) sd[r][c] += sd[r + 2][c];
    __syncthreads();
    if (r == 0) {
        float m = (sd[0][c] + sd[1][c]) / fmaxf((float)(end - beg), 1.0f);
        out[g * 16 + c] = 1.0f / (1.0f + expf(-m));
    }
}

extern "C" void kernel_launch(void* const* d_in, const int* in_sizes, int n_in,
                              void* d_out, int out_size, void* d_ws, size_t ws_size,
                              hipStream_t stream) {
    const float* x     = (const float*)d_in[0];
    const int*   ei    = (const int*)d_in[1];
    const int*   batch = (const int*)d_in[2];
    const float* W1    = (const float*)d_in[3];
    const float* b1    = (const float*)d_in[4];
    const float* W2    = (const float*)d_in[5];
    const float* b2    = (const float*)d_in[6];
    float* out = (float*)d_out;

    const int N = in_sizes[2];
    const int E = in_sizes[1] / 2;
    const int G = out_size / 16;
    const int* src = ei;
    const int* dst = ei + E;

    const int B = (N + 255) >> 8;              // 391 buckets (must be <= 512)
    const int nchunk = (E + CHUNK - 1) / CHUNK;
    const int nbound = (N + 255) / 256;

    char* w = (char*)d_ws;
    int*   bcur     = (int*)w;    w += 512 * 4;
    int*   row_ptr  = (int*)w;    w += (size_t)N * 4;
    int*   cnt      = (int*)w;    w += (size_t)N * 4;
    float* dinv     = (float*)w;  w += (size_t)N * 4;
    int*   gstart   = (int*)w;    w += 528 * 4;          // padded so hsh stays 8B-aligned
    int*   col      = (int*)w;    w += (size_t)B * CAP * 4;
    h16*   hsh      = (h16*)w;    w += (size_t)N * 64 * 2;
    h16*   h2sh     = (h16*)w;    w += (size_t)N * 16 * 2;
    h16*   h2h      = (h16*)w;    w += (size_t)N * 16 * 2;
    unsigned int* bedge = (unsigned int*)w;  w += (size_t)B * CAP * 4;

    hipMemsetAsync(bcur, 0, 512 * 4, stream);

    bscat_k <<<nchunk + nbound, 256, 0, stream>>>(src, dst, bcur, bedge, batch, gstart, E, B, N, G, nchunk);
    bcsr_k  <<<B, 256, 0, stream>>>(bedge, bcur, row_ptr, cnt, dinv, col, N, B);

    gemm1_k <<<(N + 63) / 64, 256, 0, stream>>>(x, W1, dinv, hsh, N);
    agg1_k  <<<(N + 3) / 4, 256, 0, stream>>>(hsh, row_ptr, cnt, col, dinv, b1, W2, h2sh, N);
    agg2_k  <<<((size_t)N * 16 + 255) / 256, 256, 0, stream>>>(h2sh, row_ptr, cnt, col, dinv, b2, h2h, N);
    pool_seg_k<<<G, 256, 0, stream>>>(h2h, gstart, out);
}

// Round 27
// 139.842 us; speedup vs baseline: 1.3831x; 1.1442x over previous
//
#include <hip/hip_runtime.h>
#include <hip/hip_bf16.h>

typedef float f4 __attribute__((ext_vector_type(4)));
typedef unsigned short us;
typedef unsigned int uint32;
typedef _Float16 h16;
typedef _Float16 h16x2 __attribute__((ext_vector_type(2)));
typedef _Float16 f16x8 __attribute__((ext_vector_type(8)));
typedef float f32x4v __attribute__((ext_vector_type(4)));

union h2u { uint32 u; h16 h[2]; h16x2 v; };

#define BSH 8            // 256 nodes per bucket
#define CHUNK 4096       // edges per sort workgroup
#define CAP 6144         // max edges per bucket (mean 4096, +32 sigma); also the fixed bucket stride

// ---------------- pass C (fused): chunk hist + LDS sort + padded-bucket placement (+ gbound blocks) ----------------
__global__ __launch_bounds__(256) void bscat_k(const int* __restrict__ src, const int* __restrict__ dst,
                                               int* __restrict__ bcur, unsigned int* __restrict__ bedge,
                                               const int* __restrict__ batch, int* __restrict__ gstart,
                                               int E, int B, int N, int G, int nchunk) {
    int tid = threadIdx.x;
    if (blockIdx.x >= nchunk) {   // gbound part
        int i = (blockIdx.x - nchunk) * 256 + tid;
        if (i >= N) return;
        int b = batch[i];
        int prev = (i == 0) ? -1 : batch[i - 1];
        for (int g = prev + 1; g <= b; ++g) gstart[g] = i;
        if (i == N - 1) {
            for (int g = b + 1; g <= G; ++g) gstart[g] = N;
        }
        return;
    }
    __shared__ int hist[512], lbase[512], cur2[512], gb[512];
    __shared__ int sa[512], sb[512];
    __shared__ unsigned int sedge[CHUNK];
    __shared__ unsigned short posb[CHUNK];
    int base = blockIdx.x * CHUNK;
    int n = min(CHUNK, E - base);
    for (int i = tid; i < 512; i += 256) hist[i] = 0;
    __syncthreads();
    for (int i = tid; i < n; i += 256) atomicAdd(&hist[dst[base + i] >> BSH], 1);
    __syncthreads();
    #pragma unroll
    for (int k = 0; k < 2; ++k) { int i = tid + k * 256; sa[i] = hist[i]; }
    __syncthreads();
    int* c = sa; int* nx = sb;
    for (int off = 1; off < 512; off <<= 1) {
        #pragma unroll
        for (int k = 0; k < 2; ++k) { int i = tid + k * 256; nx[i] = c[i] + (i >= off ? c[i - off] : 0); }
        __syncthreads();
        int* t = c; c = nx; nx = t;
    }
    #pragma unroll
    for (int k = 0; k < 2; ++k) {
        int i = tid + k * 256;
        int ex = c[i] - hist[i];
        lbase[i] = ex; cur2[i] = ex;
        if (i < B) gb[i] = hist[i] ? (i * CAP + atomicAdd(&bcur[i], hist[i])) : 0;
    }
    for (int t = tid; t < B; t += 256) {
        int e0 = lbase[t], e1 = e0 + hist[t];
        for (int j = e0; j < e1; ++j) posb[j] = (unsigned short)t;
    }
    __syncthreads();
    for (int i = tid; i < n; i += 256) {
        int d = dst[base + i];
        int s = src[base + i];
        int b = d >> BSH;
        int p = atomicAdd(&cur2[b], 1);
        sedge[p] = ((unsigned int)s << BSH) | (unsigned int)(d & ((1 << BSH) - 1));
    }
    __syncthreads();
    for (int i = tid; i < n; i += 256) {
        int b = posb[i];
        bedge[gb[b] + (i - lbase[b])] = sedge[i];
    }
}

// ---------------- pass D: per-bucket CSR + degrees + dinv from padded buckets ----------------
__global__ __launch_bounds__(256) void bcsr_k(const unsigned int* __restrict__ bedge,
                                              const int* __restrict__ bcur,
                                              int* __restrict__ row_ptr, int* __restrict__ cnt,
                                              float* __restrict__ dinv, int* __restrict__ col,
                                              int N, int B) {
    __shared__ int hist[256], lofs[256], cur2[256];
    __shared__ int sa[256], sb[256];
    __shared__ int cols[CAP];
    int b = blockIdx.x, tid = threadIdx.x;
    int node0 = b << BSH;
    int g0 = b * CAP;
    int n = min(bcur[b], CAP);
    hist[tid] = 0;
    __syncthreads();
    for (int i = tid; i < n; i += 256) atomicAdd(&hist[bedge[g0 + i] & 255], 1);
    __syncthreads();
    sa[tid] = hist[tid];
    __syncthreads();
    int* c = sa; int* nx = sb;
    for (int off = 1; off < 256; off <<= 1) {
        nx[tid] = c[tid] + (tid >= off ? c[tid - off] : 0);
        __syncthreads();
        int* t = c; c = nx; nx = t;
    }
    int ex = c[tid] - hist[tid];
    lofs[tid] = ex; cur2[tid] = ex;
    int node = node0 + tid;
    if (node < N) {
        int deg = hist[tid];
        cnt[node] = deg;
        row_ptr[node] = g0 + ex;
        dinv[node] = rsqrtf((float)(deg + 1));
    }
    __syncthreads();
    for (int i = tid; i < n; i += 256) {
        unsigned int e = bedge[g0 + i];
        int p = atomicAdd(&cur2[e & 255], 1);
        if (p < CAP) cols[p] = (int)(e >> BSH);
    }
    __syncthreads();
    for (int i = tid; i < n; i += 256) col[g0 + i] = (i < CAP) ? cols[i] : 0;
}

// ---------------- GEMM1 via MFMA fp16: hs_h = fp16( dinv[r] * (x @ W1) ) ----------------
// 64-row x 64-col tile per block; 4 waves, each one 16-row band; K=128 in 4 steps of 32.
__global__ __launch_bounds__(256) void gemm1_k(const float* __restrict__ x, const float* __restrict__ W1,
                                               const float* __restrict__ dinv, h16* __restrict__ hsh, int N) {
    __shared__ h16 xS[64][136];   // +8 h16 pad breaks stride-256B bank conflict
    __shared__ h16 wS[8192];      // W1 in B-fragment order: idx = ((k>>3)*64 + c)*8 + (k&7)
    const int tid = threadIdx.x;
    const int row0 = blockIdx.x * 64;

    #pragma unroll
    for (int i = 0; i < 32; ++i) {       // W1: 8192 f32, coalesced read, swizzled fp16 store
        int idx = tid + i * 256;
        int k = idx >> 6, cc = idx & 63;
        wS[(((k >> 3) * 64) + cc) * 8 + (k & 7)] = (h16)W1[idx];
    }
    #pragma unroll
    for (int it = 0; it < 8; ++it) {     // x tile: 64 rows x 32 f4
        int i = tid + it * 256;          // 0..2047
        int r = i >> 5;
        int k4 = (i & 31) * 4;
        int row = row0 + r;
        f4 v = (f4)(0.0f);
        if (row < N) v = *(const f4*)(x + (size_t)row * 128 + k4);
        xS[r][k4 + 0] = (h16)v.x; xS[r][k4 + 1] = (h16)v.y;
        xS[r][k4 + 2] = (h16)v.z; xS[r][k4 + 3] = (h16)v.w;
    }
    __syncthreads();

    const int wv = tid >> 6;     // wave = row-tile 0..3
    const int lane = tid & 63;
    const int q = lane >> 4;     // k-quarter / C row-group
    const int c = lane & 15;     // A row / B,C col
    f32x4v acc0 = {0.f, 0.f, 0.f, 0.f}, acc1 = acc0, acc2 = acc0, acc3 = acc0;
    #pragma unroll
    for (int kb = 0; kb < 4; ++kb) {
        f16x8 a = *(const f16x8*)&xS[wv * 16 + c][kb * 32 + q * 8];
        const h16* wb = &wS[(size_t)((kb * 4 + q) * 64) * 8];
        f16x8 b0 = *(const f16x8*)&wb[(0 * 16 + c) * 8];
        f16x8 b1 = *(const f16x8*)&wb[(1 * 16 + c) * 8];
        f16x8 b2 = *(const f16x8*)&wb[(2 * 16 + c) * 8];
        f16x8 b3 = *(const f16x8*)&wb[(3 * 16 + c) * 8];
        acc0 = __builtin_amdgcn_mfma_f32_16x16x32_f16(a, b0, acc0, 0, 0, 0);
        acc1 = __builtin_amdgcn_mfma_f32_16x16x32_f16(a, b1, acc1, 0, 0, 0);
        acc2 = __builtin_amdgcn_mfma_f32_16x16x32_f16(a, b2, acc2, 0, 0, 0);
        acc3 = __builtin_amdgcn_mfma_f32_16x16x32_f16(a, b3, acc3, 0, 0, 0);
    }
    #pragma unroll
    for (int j = 0; j < 4; ++j) {
        int row = row0 + wv * 16 + q * 4 + j;
        if (row < N) {
            float di = dinv[row];
            size_t base = (size_t)row * 64;
            hsh[base +  0 + c] = (h16)(acc0[j] * di);
            hsh[base + 16 + c] = (h16)(acc1[j] * di);
            hsh[base + 32 + c] = (h16)(acc2[j] * di);
            hsh[base + 48 + c] = (h16)(acc3[j] * di);
        }
    }
}

// ---------------- AGG1+GEMM2 fused: wave per node, dword (2 fp16 ch) per lane ----------------
// 16-edge unroll, packed-fp16 tree accumulate per block.
__global__ __launch_bounds__(256) void agg1_k(const h16* __restrict__ hsh, const int* __restrict__ row_ptr,
                                              const int* __restrict__ cnt, const int* __restrict__ col,
                                              const float* __restrict__ dinv, const float* __restrict__ b1,
                                              const float* __restrict__ W2, h16* __restrict__ h2sh, int N) {
    int wid = blockIdx.x * 4 + (threadIdx.x >> 6);
    int lane = threadIdx.x & 63;
    if (wid >= N) return;
    const int c16 = lane & 15;      // output channel (for the fused dot)
    const int hh  = lane >> 4;      // k-quarter 0..3
    float wreg[16];
    #pragma unroll
    for (int k = 0; k < 16; ++k) wreg[k] = W2[(hh * 16 + k) * 16 + c16];
    float bias = b1[lane];

    const int c2 = lane & 31;       // channel pair index
    const int h  = lane >> 5;       // edge subgroup 0/1
    const uint32* rowbase = (const uint32*)hsh + c2;   // + s*32 dwords = row s, channels 2c2,2c2+1

    int beg = row_ptr[wid];
    int num = cnt[wid];
    float accx = 0.0f, accy = 0.0f;
    for (int e0 = 0; e0 < num; e0 += 64) {
        int rem = num - e0;
        int el = 0;
        if (lane < rem) el = col[beg + e0 + lane];
        int m = rem < 64 ? rem : 64;
        int e = 0;
        for (; e + 16 <= m; e += 16) {     // subgroup h: 8 edges; fp16 tree then one cvt pair
            int s0 = __shfl(el, e + h);
            int s1 = __shfl(el, e + 2 + h);
            int s2 = __shfl(el, e + 4 + h);
            int s3 = __shfl(el, e + 6 + h);
            int s4 = __shfl(el, e + 8 + h);
            int s5 = __shfl(el, e + 10 + h);
            int s6 = __shfl(el, e + 12 + h);
            int s7 = __shfl(el, e + 14 + h);
            h2u u0, u1, u2, u3, u4, u5, u6, u7;
            u0.u = rowbase[(size_t)s0 * 32];
            u1.u = rowbase[(size_t)s1 * 32];
            u2.u = rowbase[(size_t)s2 * 32];
            u3.u = rowbase[(size_t)s3 * 32];
            u4.u = rowbase[(size_t)s4 * 32];
            u5.u = rowbase[(size_t)s5 * 32];
            u6.u = rowbase[(size_t)s6 * 32];
            u7.u = rowbase[(size_t)s7 * 32];
            h16x2 t01 = u0.v + u1.v;
            h16x2 t23 = u2.v + u3.v;
            h16x2 t45 = u4.v + u5.v;
            h16x2 t67 = u6.v + u7.v;
            h16x2 t03 = t01 + t23;
            h16x2 t47 = t45 + t67;
            h16x2 tt  = t03 + t47;
            accx += (float)tt[0];
            accy += (float)tt[1];
        }
        for (; e + 8 <= m; e += 8) {       // subgroup h: 4 edges
            int s0 = __shfl(el, e + h);
            int s1 = __shfl(el, e + 2 + h);
            int s2 = __shfl(el, e + 4 + h);
            int s3 = __shfl(el, e + 6 + h);
            h2u u0, u1, u2, u3;
            u0.u = rowbase[(size_t)s0 * 32];
            u1.u = rowbase[(size_t)s1 * 32];
            u2.u = rowbase[(size_t)s2 * 32];
            u3.u = rowbase[(size_t)s3 * 32];
            accx += ((float)u0.h[0] + (float)u1.h[0]) + ((float)u2.h[0] + (float)u3.h[0]);
            accy += ((float)u0.h[1] + (float)u1.h[1]) + ((float)u2.h[1] + (float)u3.h[1]);
        }
        for (; e + 4 <= m; e += 4) {       // subgroup h: edges e+h, e+2+h
            int s0 = __shfl(el, e + h);
            int s1 = __shfl(el, e + 2 + h);
            h2u u0, u1;
            u0.u = rowbase[(size_t)s0 * 32];
            u1.u = rowbase[(size_t)s1 * 32];
            accx += (float)u0.h[0] + (float)u1.h[0];
            accy += (float)u0.h[1] + (float)u1.h[1];
        }
        for (; e + 2 <= m; e += 2) {       // subgroup h: edge e+h
            int s = __shfl(el, e + h);
            h2u u; u.u = rowbase[(size_t)s * 32];
            accx += (float)u.h[0];
            accy += (float)u.h[1];
        }
        if (e < m) {                       // single leftover edge: h==0 half covers all channels
            int s = __shfl(el, e);
            if (h == 0) {
                h2u u; u.u = rowbase[(size_t)s * 32];
                accx += (float)u.h[0];
                accy += (float)u.h[1];
            }
        }
    }
    // merge the two edge subgroups
    accx += __shfl_xor(accx, 32);
    accy += __shfl_xor(accy, 32);
    // redistribute channel pairs -> lane = channel
    float ra = __shfl(accx, lane >> 1);
    float rb = __shfl(accy, lane >> 1);
    float acc = (lane & 1) ? rb : ra;

    float di = dinv[wid];
    float self = (float)hsh[(size_t)wid * 64 + lane];
    float h1v = tanhf(di * (acc + self) + bias);

    // fused h1_row @ W2: lane (hh,c16) does k = hh*16..hh*16+15, then butterfly-add quarters
    float p = 0.0f;
    #pragma unroll
    for (int k = 0; k < 16; ++k) {
        float hv = __shfl(h1v, hh * 16 + k);
        p += hv * wreg[k];
    }
    p += __shfl_xor(p, 16);
    p += __shfl_xor(p, 32);
    if (lane < 16) h2sh[(size_t)wid * 16 + lane] = (h16)(di * p);
}

// ---------------- AGG2: 16 channels, quarter-wave per node, fp16 tables both sides ----------------
__global__ __launch_bounds__(256) void agg2_k(const h16* __restrict__ h2sh, const int* __restrict__ row_ptr,
                                              const int* __restrict__ cnt, const int* __restrict__ col,
                                              const float* __restrict__ dinv, const float* __restrict__ b2,
                                              h16* __restrict__ h2h, int N) {
    int t = blockIdx.x * 256 + threadIdx.x;
    int node = t >> 4;
    int c = t & 15;
    int sub = (threadIdx.x >> 4) & 3;   // quarter within wave
    if (node >= N) return;
    int beg = row_ptr[node];
    int num = cnt[node];
    float acc = 0.0f;
    for (int e0 = 0; e0 < num; e0 += 16) {
        int rem = num - e0;
        int el = 0;
        if (c < rem) el = col[beg + e0 + c];
        int m = rem < 16 ? rem : 16;
        int e = 0;
        for (; e + 4 <= m; e += 4) {       // 4 independent loads in flight
            int s0 = __shfl(el, (sub << 4) + e + 0);
            int s1 = __shfl(el, (sub << 4) + e + 1);
            int s2 = __shfl(el, (sub << 4) + e + 2);
            int s3 = __shfl(el, (sub << 4) + e + 3);
            float v0 = (float)h2sh[(size_t)s0 * 16 + c];
            float v1 = (float)h2sh[(size_t)s1 * 16 + c];
            float v2 = (float)h2sh[(size_t)s2 * 16 + c];
            float v3 = (float)h2sh[(size_t)s3 * 16 + c];
            acc += (v0 + v1) + (v2 + v3);
        }
        for (; e < m; ++e) {
            int s = __shfl(el, (sub << 4) + e);
            acc += (float)h2sh[(size_t)s * 16 + c];
        }
    }
    float di = dinv[node];
    float self = (float)h2sh[(size_t)node * 16 + c];
    h2h[(size_t)node * 16 + c] = (h16)tanhf(di * (acc + self) + b2[c]);
}

// ---------------- segmented pool + sigmoid: one block per graph ----------------
__global__ __launch_bounds__(256) void pool_seg_k(const h16* __restrict__ h2h, const int* __restrict__ gstart,
                                                  float* __restrict__ out) {
    __shared__ float sd[16][16];   // [node-lane][channel]
    int g = blockIdx.x;
    int beg = gstart[g], end = gstart[g + 1];
    int tid = threadIdx.x;
    int c = tid & 15, r = tid >> 4;
    float acc = 0.0f;
    for (int i = beg + r; i < end; i += 16)
        acc += (float)h2h[(size_t)i * 16 + c];
    sd[r][c] = acc;
    __syncthreads();
    if (r < 8) sd[r][c] += sd[r + 8][c];
    __syncthreads();
    if (r < 4) sd[r][c] += sd[r + 4][c];
    __syncthreads();
    if (r < 2) sd[r][c] += sd[r + 2][c];
    __syncthreads();
    if (r == 0) {
        float m = (sd[0][c] + sd[1][c]) / fmaxf((float)(end - beg), 1.0f);
        out[g * 16 + c] = 1.0f / (1.0f + expf(-m));
    }
}

extern "C" void kernel_launch(void* const* d_in, const int* in_sizes, int n_in,
                              void* d_out, int out_size, void* d_ws, size_t ws_size,
                              hipStream_t stream) {
    const float* x     = (const float*)d_in[0];
    const int*   ei    = (const int*)d_in[1];
    const int*   batch = (const int*)d_in[2];
    const float* W1    = (const float*)d_in[3];
    const float* b1    = (const float*)d_in[4];
    const float* W2    = (const float*)d_in[5];
    const float* b2    = (const float*)d_in[6];
    float* out = (float*)d_out;

    const int N = in_sizes[2];
    const int E = in_sizes[1] / 2;
    const int G = out_size / 16;
    const int* src = ei;
    const int* dst = ei + E;

    const int B = (N + 255) >> 8;              // 391 buckets (must be <= 512)
    const int nchunk = (E + CHUNK - 1) / CHUNK;
    const int nbound = (N + 255) / 256;

    char* w = (char*)d_ws;
    int*   bcur     = (int*)w;    w += 512 * 4;
    int*   row_ptr  = (int*)w;    w += (size_t)N * 4;
    int*   cnt      = (int*)w;    w += (size_t)N * 4;
    float* dinv     = (float*)w;  w += (size_t)N * 4;
    int*   gstart   = (int*)w;    w += 528 * 4;          // padded so hsh stays 8B-aligned
    int*   col      = (int*)w;    w += (size_t)B * CAP * 4;
    h16*   hsh      = (h16*)w;    w += (size_t)N * 64 * 2;
    h16*   h2sh     = (h16*)w;    w += (size_t)N * 16 * 2;
    h16*   h2h      = (h16*)w;    w += (size_t)N * 16 * 2;
    unsigned int* bedge = (unsigned int*)w;  w += (size_t)B * CAP * 4;

    hipMemsetAsync(bcur, 0, 512 * 4, stream);

    bscat_k <<<nchunk + nbound, 256, 0, stream>>>(src, dst, bcur, bedge, batch, gstart, E, B, N, G, nchunk);
    bcsr_k  <<<B, 256, 0, stream>>>(bedge, bcur, row_ptr, cnt, dinv, col, N, B);

    gemm1_k <<<(N + 63) / 64, 256, 0, stream>>>(x, W1, dinv, hsh, N);
    agg1_k  <<<(N + 3) / 4, 256, 0, stream>>>(hsh, row_ptr, cnt, col, dinv, b1, W2, h2sh, N);
    agg2_k  <<<((size_t)N * 16 + 255) / 256, 256, 0, stream>>>(h2sh, row_ptr, cnt, col, dinv, b2, h2h, N);
    pool_seg_k<<<G, 256, 0, stream>>>(h2h, gstart, out);
}